// Round 2
// baseline (3353.449 us; speedup 1.0000x reference)
//
#include <hip/hip_runtime.h>

// Problem: QuantumMotivicTile — B=4, S=2048, H=16, hd=64, D=1024. I/O fp32.
// Folds: q/k/v absorb Wi;  epilogue (Wc,Wci,Wm,Wmi) folds to M (rank4) which
// folds into V:  final = softmax(q k^T/8) @ v'' + cvec,
//   Aq=Wq·Wi, Ak=Wk·Wi, Av=M·Wv·Wi, M=Wmi·Wm·Wci·Wc.
// Internal: x-tiles + Ak/Av staged as bf16 (2% bf16-floor tolerance), fp32 accum.

#define SEQ 2048
#define DM  1024
#define NH  16
#define HD  64
#define QT  64
#define KT  32

__device__ __forceinline__ float bf2f(unsigned short u) {
    return __uint_as_float(((unsigned int)u) << 16);
}
__device__ __forceinline__ unsigned short f2bf(float f) {
    unsigned int v = __float_as_uint(f);
    unsigned int r = v + 0x7FFFu + ((v >> 16) & 1u);
    return (unsigned short)(r >> 16);
}

// ---------------- weight folding (1 block, 64 threads) ----------------
// ws float layout: [0..4095] AqT (AqT[t*64+j] = Aq[j][t], fp32)
//                  [4096..4159] bq', [4160..4223] bk', [4224..4287] bv''
//                  [4288..4351] cvec
// ushort at (ws+4352): [0..4095] AkT bf16, [4096..8191] AvT bf16
__global__ __launch_bounds__(64)
void qmt_combine(
    const float* __restrict__ Wi,  const float* __restrict__ bi,
    const float* __restrict__ Wq,  const float* __restrict__ bq,
    const float* __restrict__ Wk,  const float* __restrict__ bk,
    const float* __restrict__ Wv,  const float* __restrict__ bv,
    const float* __restrict__ Wc,  const float* __restrict__ bc,
    const float* __restrict__ Wci, const float* __restrict__ bci,
    const float* __restrict__ Wm,  const float* __restrict__ bm,
    const float* __restrict__ Wmi, const float* __restrict__ bmi,
    float* __restrict__ ws)
{
    const int o = threadIdx.x;  // 0..63
    __shared__ float Wi_s[64][64];
    __shared__ float Wvi_s[64][64];
    __shared__ float M_s[64][64];
    __shared__ float bi_s[64], bvi_s[64], c1[64], c2[4];
    __shared__ float U1[4][8];
    __shared__ float U2[4][64];

    float* AqT = ws;
    float* bqv = ws + 4096;
    float* bkv = ws + 4160;
    float* bvv = ws + 4224;
    float* cv  = ws + 4288;
    unsigned short* wsub = (unsigned short*)(ws + 4352);  // AkT bf16, then AvT bf16

    for (int idx = o; idx < 4096; idx += 64)
        Wi_s[idx >> 6][idx & 63] = Wi[idx];
    bi_s[o] = bi[o];
    __syncthreads();  // (1)

    float wrow[64];
    // Aq row o -> transposed store
    for (int t = 0; t < 64; t++) wrow[t] = Wq[o * 64 + t];
    for (int i = 0; i < 64; i++) {
        float s = 0.f;
        for (int t = 0; t < 64; t++) s += wrow[t] * Wi_s[t][i];
        AqT[i * 64 + o] = s;
    }
    { float s = bq[o]; for (int t = 0; t < 64; t++) s += wrow[t] * bi_s[t]; bqv[o] = s; }
    // Ak row o -> bf16 transposed store
    for (int t = 0; t < 64; t++) wrow[t] = Wk[o * 64 + t];
    for (int i = 0; i < 64; i++) {
        float s = 0.f;
        for (int t = 0; t < 64; t++) s += wrow[t] * Wi_s[t][i];
        wsub[i * 64 + o] = f2bf(s);
    }
    { float s = bk[o]; for (int t = 0; t < 64; t++) s += wrow[t] * bi_s[t]; bkv[o] = s; }
    // Wvi = Wv@Wi row o (kept fp32 in LDS), bvi
    for (int t = 0; t < 64; t++) wrow[t] = Wv[o * 64 + t];
    for (int i = 0; i < 64; i++) {
        float s = 0.f;
        for (int t = 0; t < 64; t++) s += wrow[t] * Wi_s[t][i];
        Wvi_s[o][i] = s;
    }
    { float s = bv[o]; for (int t = 0; t < 64; t++) s += wrow[t] * bi_s[t]; bvi_s[o] = s; }
    // U1 = Wm @ Wci  (4x8)
    if (o < 32) {
        int a = o >> 3, c = o & 7;
        float s = 0.f;
        for (int t = 0; t < 64; t++) s += Wm[a * 64 + t] * Wci[t * 8 + c];
        U1[a][c] = s;
    }
    __syncthreads();  // (2)
    // U2 = U1 @ Wc  (4x64), column o
    for (int a = 0; a < 4; a++) {
        float s = 0.f;
        for (int cc = 0; cc < 8; cc++) s += U1[a][cc] * Wc[cc * 64 + o];
        U2[a][o] = s;
    }
    // c1 = Wci@bc + bci
    { float s = bci[o]; for (int j = 0; j < 8; j++) s += Wci[o * 8 + j] * bc[j]; c1[o] = s; }
    __syncthreads();  // (3)
    // M = Wmi @ U2, row o
    for (int i = 0; i < 64; i++) {
        float s = 0.f;
        for (int a = 0; a < 4; a++) s += Wmi[o * 4 + a] * U2[a][i];
        M_s[o][i] = s;
    }
    // c2 = Wm@c1 + bm
    if (o < 4) { float s = bm[o]; for (int i = 0; i < 64; i++) s += Wm[o * 64 + i] * c1[i]; c2[o] = s; }
    __syncthreads();  // (4)
    // cvec = Wmi@c2 + bmi
    { float s = bmi[o]; for (int a = 0; a < 4; a++) s += Wmi[o * 4 + a] * c2[a]; cv[o] = s; }
    // Av = M @ Wvi row o -> bf16 transposed; bv'' = M@bvi
    for (int i = 0; i < 64; i++) {
        float s = 0.f;
        for (int t = 0; t < 64; t++) s += M_s[o][t] * Wvi_s[t][i];
        wsub[4096 + i * 64 + o] = f2bf(s);
    }
    { float s = 0.f; for (int t = 0; t < 64; t++) s += M_s[o][t] * bvi_s[t]; bvv[o] = s; }
}

// ---------------- flash attention ----------------
// grid (32 q-tiles, 64 b*h), block 256. Q-tile 64, K-tile 32.
__global__ __launch_bounds__(256, 2)
void qmt_attn(const float* __restrict__ x,
              const float* __restrict__ wsf,
              float* __restrict__ out)
{
    // strides chosen for 16B-aligned float4/uint4 LDS ops + conflict-freedom
    __shared__ __align__(16) unsigned short qs[QT][68];   // x q-tile bf16, then q*0.125 (bf16)
    __shared__ __align__(16) float ubuf[QT * 36];          // ps[64][36] fp32 | x k-tile bf16 [32][68]
    __shared__ __align__(16) float ks[HD][48];             // k transposed [dim][key]
    __shared__ __align__(16) float vs[KT][68];             // v [key][dim]
    __shared__ __align__(16) unsigned short Akb[HD][72];   // AkT bf16 [t][j]
    __shared__ __align__(16) unsigned short Avb[HD][72];   // AvT bf16 [t][j]
    __shared__ float pm[QT][4];
    __shared__ float ms[QT], ls[QT], als[QT];
    __shared__ float bks[HD], bvs[HD], cvs[HD];

    const int tid = threadIdx.x;
    const int b = blockIdx.y >> 4;
    const int h = blockIdx.y & 15;
    const int qbase = blockIdx.x * QT;

    const unsigned short* wub = (const unsigned short*)(wsf + 4352);

    for (int idx = tid; idx < 4096; idx += 256) {
        int t = idx >> 6, j = idx & 63;
        Akb[t][j] = wub[idx];
        Avb[t][j] = wub[4096 + idx];
    }
    if (tid < 64) {
        bks[tid] = wsf[4160 + tid];
        bvs[tid] = wsf[4224 + tid];
        cvs[tid] = wsf[4288 + tid];
        ms[tid] = -1e30f;
        ls[tid] = 0.f;
    }
    {   // stage x q-tile (fp32 global -> bf16 LDS)
        const float* xq = x + ((size_t)(b * SEQ + qbase) * DM + h * HD);
        for (int idx = tid; idx < QT * 16; idx += 256) {
            int r = idx >> 4, c4 = (idx & 15) * 4;
            float4 u = *(const float4*)(xq + (size_t)r * DM + c4);
            ushort4 s;
            s.x = f2bf(u.x); s.y = f2bf(u.y); s.z = f2bf(u.z); s.w = f2bf(u.w);
            *(ushort4*)&qs[r][c4] = s;
        }
    }
    __syncthreads();

    const int r   = tid >> 2;        // q-row (scores / exp / O / q-compute)
    const int c0q = (tid & 3) * 16;  // q dims
    const int c0s = (tid & 3) * 8;   // score cols
    const int d0  = (tid & 3) * 16;  // O dims
    const int kk  = tid >> 3;        // key row (kv stage)
    const int c0k = (tid & 7) * 8;   // kv dims

    // q = (x @ Aq^T + bq) * 0.125  -> bf16 back into qs
    {
        float acc[16];
        #pragma unroll
        for (int i = 0; i < 16; i++) acc[i] = wsf[4096 + c0q + i];
        for (int t = 0; t < 64; t++) {
            float xv = bf2f(qs[r][t]);
            const float* wrow = wsf + t * 64 + c0q;
            float4 w0 = *(const float4*)(wrow);
            float4 w1 = *(const float4*)(wrow + 4);
            float4 w2 = *(const float4*)(wrow + 8);
            float4 w3 = *(const float4*)(wrow + 12);
            acc[0]  += xv * w0.x; acc[1]  += xv * w0.y; acc[2]  += xv * w0.z; acc[3]  += xv * w0.w;
            acc[4]  += xv * w1.x; acc[5]  += xv * w1.y; acc[6]  += xv * w1.z; acc[7]  += xv * w1.w;
            acc[8]  += xv * w2.x; acc[9]  += xv * w2.y; acc[10] += xv * w2.z; acc[11] += xv * w2.w;
            acc[12] += xv * w3.x; acc[13] += xv * w3.y; acc[14] += xv * w3.z; acc[15] += xv * w3.w;
        }
        __syncthreads();  // all reads of x-tile done before q overwrites it
        #pragma unroll
        for (int i = 0; i < 16; i++) qs[r][c0q + i] = f2bf(acc[i] * 0.125f);
    }

    float o_acc[16];
    #pragma unroll
    for (int i = 0; i < 16; i++) o_acc[i] = 0.f;

    float* ps = ubuf;                              // [64][36]
    unsigned short* xsb = (unsigned short*)ubuf;   // [32][68] bf16

    for (int kt = 0; kt < SEQ / KT; kt++) {
        __syncthreads();  // (A) prev iter done (ps/vs reads) before overwrite
        {   // stage x k-tile (fp32 global -> bf16 LDS)
            const float* xk = x + ((size_t)(b * SEQ + kt * KT) * DM + h * HD);
            for (int idx = tid; idx < KT * 16; idx += 256) {
                int rr = idx >> 4, c4 = (idx & 15) * 4;
                float4 u = *(const float4*)(xk + (size_t)rr * DM + c4);
                ushort4 s;
                s.x = f2bf(u.x); s.y = f2bf(u.y); s.z = f2bf(u.z); s.w = f2bf(u.w);
                *(ushort4*)&xsb[rr * 68 + c4] = s;
            }
        }
        __syncthreads();  // (B)
        {   // k,v tiles:  k -> ks[dim][key], v -> vs[key][dim]
            float ak[8], av[8];
            #pragma unroll
            for (int i = 0; i < 8; i++) { ak[i] = bks[c0k + i]; av[i] = bvs[c0k + i]; }
            for (int t = 0; t < 64; t++) {
                float xv = bf2f(xsb[kk * 68 + t]);
                uint4 wk = *(const uint4*)&Akb[t][c0k];
                uint4 wv = *(const uint4*)&Avb[t][c0k];
                ak[0] += xv * __uint_as_float(wk.x << 16);
                ak[1] += xv * __uint_as_float(wk.x & 0xffff0000u);
                ak[2] += xv * __uint_as_float(wk.y << 16);
                ak[3] += xv * __uint_as_float(wk.y & 0xffff0000u);
                ak[4] += xv * __uint_as_float(wk.z << 16);
                ak[5] += xv * __uint_as_float(wk.z & 0xffff0000u);
                ak[6] += xv * __uint_as_float(wk.w << 16);
                ak[7] += xv * __uint_as_float(wk.w & 0xffff0000u);
                av[0] += xv * __uint_as_float(wv.x << 16);
                av[1] += xv * __uint_as_float(wv.x & 0xffff0000u);
                av[2] += xv * __uint_as_float(wv.y << 16);
                av[3] += xv * __uint_as_float(wv.y & 0xffff0000u);
                av[4] += xv * __uint_as_float(wv.z << 16);
                av[5] += xv * __uint_as_float(wv.z & 0xffff0000u);
                av[6] += xv * __uint_as_float(wv.w << 16);
                av[7] += xv * __uint_as_float(wv.w & 0xffff0000u);
            }
            #pragma unroll
            for (int i = 0; i < 8; i++) ks[c0k + i][kk] = ak[i];
            *(float4*)&vs[kk][c0k]     = make_float4(av[0], av[1], av[2], av[3]);
            *(float4*)&vs[kk][c0k + 4] = make_float4(av[4], av[5], av[6], av[7]);
        }
        __syncthreads();  // (C)
        {   // scores (q pre-scaled)
            float sc[8];
            #pragma unroll
            for (int i = 0; i < 8; i++) sc[i] = 0.f;
            for (int t = 0; t < 64; t++) {
                float qv = bf2f(qs[r][t]);
                float4 k0 = *(const float4*)&ks[t][c0s];
                float4 k1 = *(const float4*)&ks[t][c0s + 4];
                sc[0] += qv * k0.x; sc[1] += qv * k0.y; sc[2] += qv * k0.z; sc[3] += qv * k0.w;
                sc[4] += qv * k1.x; sc[5] += qv * k1.y; sc[6] += qv * k1.z; sc[7] += qv * k1.w;
            }
            float lmax = sc[0];
            #pragma unroll
            for (int i = 1; i < 8; i++) lmax = fmaxf(lmax, sc[i]);
            *(float4*)&ps[r * 36 + c0s]     = make_float4(sc[0], sc[1], sc[2], sc[3]);
            *(float4*)&ps[r * 36 + c0s + 4] = make_float4(sc[4], sc[5], sc[6], sc[7]);
            pm[r][tid & 3] = lmax;
        }
        __syncthreads();  // (D)
        if (tid < 64) {
            float rm = fmaxf(fmaxf(pm[tid][0], pm[tid][1]), fmaxf(pm[tid][2], pm[tid][3]));
            float nm = fmaxf(ms[tid], rm);
            als[tid] = __expf(ms[tid] - nm);
            ms[tid] = nm;
        }
        __syncthreads();  // (E)
        {   // exponentiate + partial row sums
            float mr = ms[r];
            float4 p0 = *(const float4*)&ps[r * 36 + c0s];
            float4 p1 = *(const float4*)&ps[r * 36 + c0s + 4];
            p0.x = __expf(p0.x - mr); p0.y = __expf(p0.y - mr);
            p0.z = __expf(p0.z - mr); p0.w = __expf(p0.w - mr);
            p1.x = __expf(p1.x - mr); p1.y = __expf(p1.y - mr);
            p1.z = __expf(p1.z - mr); p1.w = __expf(p1.w - mr);
            *(float4*)&ps[r * 36 + c0s]     = p0;
            *(float4*)&ps[r * 36 + c0s + 4] = p1;
            pm[r][tid & 3] = p0.x + p0.y + p0.z + p0.w + p1.x + p1.y + p1.z + p1.w;
        }
        __syncthreads();  // (F)
        if (tid < 64)
            ls[tid] = ls[tid] * als[tid] + (pm[tid][0] + pm[tid][1] + pm[tid][2] + pm[tid][3]);
        {   // O update
            float a = als[r];
            #pragma unroll
            for (int i = 0; i < 16; i++) o_acc[i] *= a;
            for (int k2 = 0; k2 < KT; k2++) {
                float p = ps[r * 36 + k2];
                float4 v0 = *(const float4*)&vs[k2][d0];
                float4 v1 = *(const float4*)&vs[k2][d0 + 4];
                float4 v2 = *(const float4*)&vs[k2][d0 + 8];
                float4 v3 = *(const float4*)&vs[k2][d0 + 12];
                o_acc[0]  += p * v0.x; o_acc[1]  += p * v0.y; o_acc[2]  += p * v0.z; o_acc[3]  += p * v0.w;
                o_acc[4]  += p * v1.x; o_acc[5]  += p * v1.y; o_acc[6]  += p * v1.z; o_acc[7]  += p * v1.w;
                o_acc[8]  += p * v2.x; o_acc[9]  += p * v2.y; o_acc[10] += p * v2.z; o_acc[11] += p * v2.w;
                o_acc[12] += p * v3.x; o_acc[13] += p * v3.y; o_acc[14] += p * v3.z; o_acc[15] += p * v3.w;
            }
        }
    }
    __syncthreads();
    {   // epilogue: /l, +cvec, fp32 store (4x float4 = 64B)
        float inv = 1.f / ls[r];
        float* op = out + ((size_t)(b * SEQ + qbase + r) * DM + h * HD + d0);
        float4 o0 = make_float4(o_acc[0]  * inv + cvs[d0 + 0],  o_acc[1]  * inv + cvs[d0 + 1],
                                o_acc[2]  * inv + cvs[d0 + 2],  o_acc[3]  * inv + cvs[d0 + 3]);
        float4 o1 = make_float4(o_acc[4]  * inv + cvs[d0 + 4],  o_acc[5]  * inv + cvs[d0 + 5],
                                o_acc[6]  * inv + cvs[d0 + 6],  o_acc[7]  * inv + cvs[d0 + 7]);
        float4 o2 = make_float4(o_acc[8]  * inv + cvs[d0 + 8],  o_acc[9]  * inv + cvs[d0 + 9],
                                o_acc[10] * inv + cvs[d0 + 10], o_acc[11] * inv + cvs[d0 + 11]);
        float4 o3 = make_float4(o_acc[12] * inv + cvs[d0 + 12], o_acc[13] * inv + cvs[d0 + 13],
                                o_acc[14] * inv + cvs[d0 + 14], o_acc[15] * inv + cvs[d0 + 15]);
        ((float4*)op)[0] = o0;
        ((float4*)op)[1] = o1;
        ((float4*)op)[2] = o2;
        ((float4*)op)[3] = o3;
    }
}

extern "C" void kernel_launch(void* const* d_in, const int* in_sizes, int n_in,
                              void* d_out, int out_size, void* d_ws, size_t ws_size,
                              hipStream_t stream) {
    const float* x = (const float*)d_in[0];
    float* wsf = (float*)d_ws;

    qmt_combine<<<1, 64, 0, stream>>>(
        (const float*)d_in[1],  (const float*)d_in[2],
        (const float*)d_in[3],  (const float*)d_in[4],
        (const float*)d_in[5],  (const float*)d_in[6],
        (const float*)d_in[7],  (const float*)d_in[8],
        (const float*)d_in[9],  (const float*)d_in[10],
        (const float*)d_in[11], (const float*)d_in[12],
        (const float*)d_in[13], (const float*)d_in[14],
        (const float*)d_in[15], (const float*)d_in[16],
        wsf);

    dim3 grid(SEQ / QT, 64);
    qmt_attn<<<grid, 256, 0, stream>>>(x, wsf, (float*)d_out);
}

// Round 3
// 348.146 us; speedup vs baseline: 9.6323x; 9.6323x over previous
//
#include <hip/hip_runtime.h>

// QuantumMotivicTile — B=4, S=2048, H=16, hd=64, D=1024, fp32 I/O.
// final = softmax(q k^T / 8) @ v'' + ecv
//   Aq = 0.125·Wq·Wi (bq folded+scaled), Ak = Wk·Wi (bias cancels in softmax),
//   Av = M·Wv·Wi with M = Wmi·Wm·Wci·Wc (rank 4), ecv = M·(Wv·bi+bv) + cvec.
// MFMA v_mfma_f32_32x32x16_bf16 for Qproj/KVproj/QK^T/PV; fp32 softmax.

#define SEQ 2048
#define DM  1024
#define HD  64

typedef short bf16x8 __attribute__((ext_vector_type(8)));
typedef float f32x16 __attribute__((ext_vector_type(16)));

#define MFMA32 __builtin_amdgcn_mfma_f32_32x32x16_bf16

__device__ __forceinline__ unsigned short f2bf(float f) {
    unsigned int v = __float_as_uint(f);
    unsigned int r = v + 0x7FFFu + ((v >> 16) & 1u);
    return (unsigned short)(r >> 16);
}
// pack 2 fp32 -> 2 bf16 (round-half-up) in one dword: low16 = bf(a), high16 = bf(b)
__device__ __forceinline__ unsigned int pk2r(float a, float b) {
    return __builtin_amdgcn_perm(__float_as_uint(b) + 0x8000u,
                                 __float_as_uint(a) + 0x8000u, 0x07060302u);
}
// truncating pack (for x staging)
__device__ __forceinline__ unsigned int pk2t(float a, float b) {
    return __builtin_amdgcn_perm(__float_as_uint(b), __float_as_uint(a), 0x07060302u);
}

__device__ __forceinline__ f32x16 z16() {
    f32x16 v;
    #pragma unroll
    for (int i = 0; i < 16; i++) v[i] = 0.f;
    return v;
}

// acc[0..16) = (row · L)[i0..i0+16)  where row is 64 floats, L is 64x64 (row-major)
__device__ __forceinline__ void mm16(const float* __restrict__ wrow,
                                     const float* __restrict__ L, int i0,
                                     float* __restrict__ acc) {
    #pragma unroll
    for (int ii = 0; ii < 16; ii++) acc[ii] = 0.f;
    for (int t = 0; t < 64; t += 4) {
        float4 w4 = *(const float4*)(wrow + t);
        #pragma unroll
        for (int d = 0; d < 4; d++) {
            float wv = (d == 0) ? w4.x : (d == 1) ? w4.y : (d == 2) ? w4.z : w4.w;
            const float* lr = L + (t + d) * 64 + i0;
            float4 a = *(const float4*)lr;
            float4 b = *(const float4*)(lr + 4);
            float4 c = *(const float4*)(lr + 8);
            float4 e = *(const float4*)(lr + 12);
            acc[0] += wv * a.x;  acc[1] += wv * a.y;  acc[2]  += wv * a.z;  acc[3]  += wv * a.w;
            acc[4] += wv * b.x;  acc[5] += wv * b.y;  acc[6]  += wv * b.z;  acc[7]  += wv * b.w;
            acc[8] += wv * c.x;  acc[9] += wv * c.y;  acc[10] += wv * c.z;  acc[11] += wv * c.w;
            acc[12] += wv * e.x; acc[13] += wv * e.y; acc[14] += wv * e.z;  acc[15] += wv * e.w;
        }
    }
}

// ---------------- weight folding ----------------
// ws floats: [0..63] bq' (×0.125), [64..127] ecv
// ushort at ws+128 floats: [0..4095] Aq (×0.125), [4096..8191] Ak, [8192..12287] Av
// all row-major [dout][din] bf16.
__global__ __launch_bounds__(256)
void qmt_combine(const float* __restrict__ Wi,  const float* __restrict__ bi,
                 const float* __restrict__ Wq,  const float* __restrict__ bq,
                 const float* __restrict__ Wk,  const float* __restrict__ bk,
                 const float* __restrict__ Wv,  const float* __restrict__ bv,
                 const float* __restrict__ Wc,  const float* __restrict__ bc,
                 const float* __restrict__ Wci, const float* __restrict__ bci,
                 const float* __restrict__ Wm,  const float* __restrict__ bm,
                 const float* __restrict__ Wmi, const float* __restrict__ bmi,
                 float* __restrict__ ws) {
    const int tid = threadIdx.x;
    const int o = tid & 63;
    const int i0 = (tid >> 6) * 16;
    const bool lead = (tid < 64);

    __shared__ float Wi_s[64 * 64];
    __shared__ float Wvi_s[64 * 64];
    __shared__ float M_s[64 * 64];
    __shared__ float bi_s[64], bvi_s[64], c1[64], c2[4];
    __shared__ float U1[32], U2[4 * 64];

    unsigned short* wsu = (unsigned short*)(ws + 128);

    for (int idx = tid; idx < 4096; idx += 256) Wi_s[idx] = Wi[idx];
    if (lead) bi_s[o] = bi[o];
    __syncthreads();

    float acc[16];
    // Aq = Wq·Wi  (×0.125)
    mm16(Wq + o * 64, Wi_s, i0, acc);
    #pragma unroll
    for (int ii = 0; ii < 16; ii++) wsu[o * 64 + i0 + ii] = f2bf(acc[ii] * 0.125f);
    if (lead) {
        float s = bq[o];
        for (int t = 0; t < 64; t++) s += Wq[o * 64 + t] * bi_s[t];
        ws[o] = s * 0.125f;
    }
    // Ak = Wk·Wi  (bias dropped — cancels in softmax)
    mm16(Wk + o * 64, Wi_s, i0, acc);
    #pragma unroll
    for (int ii = 0; ii < 16; ii++) wsu[4096 + o * 64 + i0 + ii] = f2bf(acc[ii]);
    // Wvi = Wv·Wi (fp32 LDS), bvi
    mm16(Wv + o * 64, Wi_s, i0, acc);
    #pragma unroll
    for (int ii = 0; ii < 16; ii++) Wvi_s[o * 64 + i0 + ii] = acc[ii];
    if (lead) {
        float s = bv[o];
        for (int t = 0; t < 64; t++) s += Wv[o * 64 + t] * bi_s[t];
        bvi_s[o] = s;
    }
    // U1 = Wm·Wci (4x8)
    if (tid < 32) {
        int a = tid >> 3, c = tid & 7;
        float s = 0.f;
        for (int t = 0; t < 64; t++) s += Wm[a * 64 + t] * Wci[t * 8 + c];
        U1[a * 8 + c] = s;
    }
    __syncthreads();
    if (lead) {
        for (int a = 0; a < 4; a++) {
            float s = 0.f;
            for (int cc = 0; cc < 8; cc++) s += U1[a * 8 + cc] * Wc[cc * 64 + o];
            U2[a * 64 + o] = s;
        }
        float s = bci[o];
        for (int j = 0; j < 8; j++) s += Wci[o * 8 + j] * bc[j];
        c1[o] = s;
    }
    __syncthreads();
    // M = Wmi·U2
    #pragma unroll
    for (int ii = 0; ii < 16; ii++) {
        float s = 0.f;
        for (int a = 0; a < 4; a++) s += Wmi[o * 4 + a] * U2[a * 64 + i0 + ii];
        M_s[o * 64 + i0 + ii] = s;
    }
    if (tid < 4) {
        float s = bm[tid];
        for (int i = 0; i < 64; i++) s += Wm[tid * 64 + i] * c1[i];
        c2[tid] = s;
    }
    __syncthreads();
    // Av = M·Wvi ; ecv = (Wmi·c2 + bmi) + M·bvi
    mm16(M_s + o * 64, Wvi_s, i0, acc);
    #pragma unroll
    for (int ii = 0; ii < 16; ii++) wsu[8192 + o * 64 + i0 + ii] = f2bf(acc[ii]);
    if (lead) {
        float bvv = 0.f;
        for (int t = 0; t < 64; t++) bvv += M_s[o * 64 + t] * bvi_s[t];
        float cvv = bmi[o];
        for (int a = 0; a < 4; a++) cvv += Wmi[o * 4 + a] * c2[a];
        ws[64 + o] = cvv + bvv;
    }
}

// ---------------- MFMA flash attention ----------------
// grid (16 q-tiles, 64 b*h), block 256 = 4 waves. QT=128 (32 qrows/wave), KT=64.
__global__ __launch_bounds__(256, 3)
void qmt_attn(const float* __restrict__ x, const float* __restrict__ wsf,
              float* __restrict__ out) {
    __shared__ __align__(16) unsigned short ps_s[128 * 72];  // qs (prologue) then P; wave-local rows
    __shared__ __align__(16) unsigned short ks_s[64 * 72];   // K [key][dout]
    __shared__ __align__(16) unsigned short vt_s[64 * 72];   // V^T [dout][key]
    __shared__ float als_l[128];
    __shared__ float ls_l[128];

    const int tid = threadIdx.x;
    const int w = tid >> 6;
    const int lane = tid & 63;
    const int ln = lane & 31;
    const int h = lane >> 5;
    const int b = blockIdx.y >> 4;
    const int hh = blockIdx.y & 15;
    const int qbase = blockIdx.x * 128;

    const unsigned short* wsu = (const unsigned short*)(wsf + 128);

    // persistent weight fragments: Ak A-frags & Av B-frags for dout-tile (w&1)
    bf16x8 akf[4], avf[4];
    #pragma unroll
    for (int c = 0; c < 4; c++) {
        int row = (w & 1) * 32 + ln;
        int col = c * 16 + h * 8;
        akf[c] = *(const bf16x8*)(wsu + 4096 + row * 64 + col);
        avf[c] = *(const bf16x8*)(wsu + 8192 + row * 64 + col);
    }
    const float ec0 = wsf[64 + ln];
    const float ec1 = wsf[96 + ln];

    // ---- Q projection: Q^T = Aq·x^T, pack to qs[qrow][dout], reload B-frags ----
    bf16x8 qf[4];
    {
        bf16x8 xq[4];
        const float* xrow = x + ((size_t)(b * SEQ + qbase + w * 32 + ln) * DM + hh * HD);
        #pragma unroll
        for (int c = 0; c < 4; c++) {
            const float* p = xrow + c * 16 + h * 8;
            float4 f0 = *(const float4*)p;
            float4 f1 = *(const float4*)(p + 4);
            union { bf16x8 v; unsigned int u[4]; } t;
            t.u[0] = pk2t(f0.x, f0.y); t.u[1] = pk2t(f0.z, f0.w);
            t.u[2] = pk2t(f1.x, f1.y); t.u[3] = pk2t(f1.z, f1.w);
            xq[c] = t.v;
        }
        #pragma unroll
        for (int m = 0; m < 2; m++) {
            f32x16 acc;
            #pragma unroll
            for (int g = 0; g < 4; g++) {  // init with bq' (dout rows 8g+4h+0..3)
                float4 b4 = *(const float4*)&wsf[m * 32 + 8 * g + 4 * h];
                acc[4 * g + 0] = b4.x; acc[4 * g + 1] = b4.y;
                acc[4 * g + 2] = b4.z; acc[4 * g + 3] = b4.w;
            }
            #pragma unroll
            for (int c = 0; c < 4; c++) {
                bf16x8 aq = *(const bf16x8*)(wsu + (m * 32 + ln) * 64 + c * 16 + h * 8);
                acc = MFMA32(aq, xq[c], acc, 0, 0, 0);
            }
            #pragma unroll
            for (int g = 0; g < 4; g++) {
                uint2 pw;
                pw.x = pk2r(acc[4 * g + 0], acc[4 * g + 1]);
                pw.y = pk2r(acc[4 * g + 2], acc[4 * g + 3]);
                *(uint2*)&ps_s[(w * 32 + ln) * 72 + m * 32 + 8 * g + 4 * h] = pw;
            }
        }
        #pragma unroll
        for (int c = 0; c < 4; c++)
            qf[c] = *(const bf16x8*)&ps_s[(w * 32 + ln) * 72 + c * 16 + h * 8];
    }

    f32x16 o0 = z16(), o1 = z16();
    float m_i = -1e30f, l_i = 0.f;

    const int krl = (w >> 1) * 32 + ln;  // this wave's staged key row / ks write row
    const int dt32 = (w & 1) * 32;       // this wave's projected dout tile base

    for (int kt = 0; kt < SEQ / 64; kt++) {
        // ---- phase 1: x -> frags (global), project K^T and V, pack to LDS ----
        bf16x8 xf[4];
        const float* xr = x + ((size_t)(b * SEQ + kt * 64 + krl) * DM + hh * HD);
        #pragma unroll
        for (int c = 0; c < 4; c++) {
            const float* p = xr + c * 16 + h * 8;
            float4 f0 = *(const float4*)p;
            float4 f1 = *(const float4*)(p + 4);
            union { bf16x8 v; unsigned int u[4]; } t;
            t.u[0] = pk2t(f0.x, f0.y); t.u[1] = pk2t(f0.z, f0.w);
            t.u[2] = pk2t(f1.x, f1.y); t.u[3] = pk2t(f1.z, f1.w);
            xf[c] = t.v;
        }
        f32x16 kacc = z16(), vacc = z16();
        #pragma unroll
        for (int c = 0; c < 4; c++) kacc = MFMA32(akf[c], xf[c], kacc, 0, 0, 0);  // K^T: m=dout, n=key
        #pragma unroll
        for (int c = 0; c < 4; c++) vacc = MFMA32(xf[c], avf[c], vacc, 0, 0, 0);  // V: m=key, n=dout
        #pragma unroll
        for (int g = 0; g < 4; g++) {
            uint2 pk_, pv_;
            pk_.x = pk2r(kacc[4 * g + 0], kacc[4 * g + 1]);
            pk_.y = pk2r(kacc[4 * g + 2], kacc[4 * g + 3]);
            *(uint2*)&ks_s[krl * 72 + dt32 + 8 * g + 4 * h] = pk_;
            pv_.x = pk2r(vacc[4 * g + 0], vacc[4 * g + 1]);
            pv_.y = pk2r(vacc[4 * g + 2], vacc[4 * g + 3]);
            *(uint2*)&vt_s[(dt32 + ln) * 72 + (w >> 1) * 32 + 8 * g + 4 * h] = pv_;
        }
        __syncthreads();  // (i) ks/vt complete

        // ---- phase 2: S^T = K·Q^T + online softmax ----
        f32x16 st0 = z16(), st1 = z16();
        #pragma unroll
        for (int c = 0; c < 4; c++) {
            bf16x8 k0 = *(const bf16x8*)&ks_s[ln * 72 + c * 16 + h * 8];
            bf16x8 k1 = *(const bf16x8*)&ks_s[(32 + ln) * 72 + c * 16 + h * 8];
            st0 = MFMA32(k0, qf[c], st0, 0, 0, 0);
            st1 = MFMA32(k1, qf[c], st1, 0, 0, 0);
        }
        float mx = st0[0];
        #pragma unroll
        for (int i = 1; i < 16; i++) mx = fmaxf(mx, st0[i]);
        #pragma unroll
        for (int i = 0; i < 16; i++) mx = fmaxf(mx, st1[i]);
        mx = fmaxf(mx, __shfl_xor(mx, 32));
        const float mn = fmaxf(m_i, mx);
        const float al = __expf(m_i - mn);
        float ss = 0.f;
        #pragma unroll
        for (int i = 0; i < 16; i++) { st0[i] = __expf(st0[i] - mn); ss += st0[i]; }
        #pragma unroll
        for (int i = 0; i < 16; i++) { st1[i] = __expf(st1[i] - mn); ss += st1[i]; }
        ss += __shfl_xor(ss, 32);
        l_i = l_i * al + ss;
        m_i = mn;
        if (lane < 32) als_l[w * 32 + lane] = al;
        #pragma unroll
        for (int g = 0; g < 4; g++) {
            uint2 p0, p1;
            p0.x = pk2r(st0[4 * g + 0], st0[4 * g + 1]);
            p0.y = pk2r(st0[4 * g + 2], st0[4 * g + 3]);
            *(uint2*)&ps_s[(w * 32 + ln) * 72 + 8 * g + 4 * h] = p0;
            p1.x = pk2r(st1[4 * g + 0], st1[4 * g + 1]);
            p1.y = pk2r(st1[4 * g + 2], st1[4 * g + 3]);
            *(uint2*)&ps_s[(w * 32 + ln) * 72 + 32 + 8 * g + 4 * h] = p1;
        }
        #pragma unroll
        for (int g = 0; g < 4; g++) {  // rescale O by alpha[q] (q = 8g+4h+i)
            float4 a4 = *(const float4*)&als_l[w * 32 + 8 * g + 4 * h];
            o0[4 * g + 0] *= a4.x; o0[4 * g + 1] *= a4.y;
            o0[4 * g + 2] *= a4.z; o0[4 * g + 3] *= a4.w;
            o1[4 * g + 0] *= a4.x; o1[4 * g + 1] *= a4.y;
            o1[4 * g + 2] *= a4.z; o1[4 * g + 3] *= a4.w;
        }
        // ---- phase 3: O += P·V ----
        #pragma unroll
        for (int c = 0; c < 4; c++) {
            bf16x8 pf = *(const bf16x8*)&ps_s[(w * 32 + ln) * 72 + c * 16 + h * 8];
            bf16x8 v0 = *(const bf16x8*)&vt_s[ln * 72 + c * 16 + h * 8];
            bf16x8 v1 = *(const bf16x8*)&vt_s[(32 + ln) * 72 + c * 16 + h * 8];
            o0 = MFMA32(pf, v0, o0, 0, 0, 0);
            o1 = MFMA32(pf, v1, o1, 0, 0, 0);
        }
        __syncthreads();  // (ii) all reads of ks/vt done before next overwrite
    }

    // ---- epilogue ----
    if (lane < 32) ls_l[w * 32 + lane] = l_i;
    #pragma unroll
    for (int g = 0; g < 4; g++) {
        float4 l4 = *(const float4*)&ls_l[w * 32 + 8 * g + 4 * h];
        float4 iv = make_float4(1.f / l4.x, 1.f / l4.y, 1.f / l4.z, 1.f / l4.w);
        #pragma unroll
        for (int i = 0; i < 4; i++) {
            float ivv = (i == 0) ? iv.x : (i == 1) ? iv.y : (i == 2) ? iv.z : iv.w;
            int q = qbase + w * 32 + 8 * g + 4 * h + i;
            float* orow = out + ((size_t)(b * SEQ + q) * DM + hh * HD);
            orow[ln] = o0[4 * g + i] * ivv + ec0;
            orow[32 + ln] = o1[4 * g + i] * ivv + ec1;
        }
    }
}

extern "C" void kernel_launch(void* const* d_in, const int* in_sizes, int n_in,
                              void* d_out, int out_size, void* d_ws, size_t ws_size,
                              hipStream_t stream) {
    const float* x = (const float*)d_in[0];
    float* wsf = (float*)d_ws;

    qmt_combine<<<1, 256, 0, stream>>>(
        (const float*)d_in[1],  (const float*)d_in[2],
        (const float*)d_in[3],  (const float*)d_in[4],
        (const float*)d_in[5],  (const float*)d_in[6],
        (const float*)d_in[7],  (const float*)d_in[8],
        (const float*)d_in[9],  (const float*)d_in[10],
        (const float*)d_in[11], (const float*)d_in[12],
        (const float*)d_in[13], (const float*)d_in[14],
        (const float*)d_in[15], (const float*)d_in[16],
        wsf);

    dim3 grid(SEQ / 128, 64);
    qmt_attn<<<grid, 256, 0, stream>>>(x, wsf, (float*)d_out);
}

// Round 4
// 264.710 us; speedup vs baseline: 12.6684x; 1.3152x over previous
//
#include <hip/hip_runtime.h>

// QuantumMotivicTile — B=4, S=2048, H=16, hd=64, D=1024, fp32 I/O.
// final = softmax(q k^T / 8) @ v'' + ecv
//   Aq = 0.125·Wq·Wi (bq folded+scaled), Ak = Wk·Wi (bias cancels in softmax),
//   Av = M·Wv·Wi with M = Wmi·Wm·Wci·Wc (rank 4), ecv = M·(Wv·bi+bv) + cvec.
// R4: K/V projected ONCE by a prepass into d_ws (bf16), attention K-loop is
// double-buffered with 1 barrier/iter. Fallback to R3 kernel if ws too small.

#define SEQ 2048
#define DM  1024
#define HD  64

typedef short bf16x8 __attribute__((ext_vector_type(8)));
typedef unsigned short u16x8 __attribute__((ext_vector_type(8)));
typedef float f32x16 __attribute__((ext_vector_type(16)));

#define MFMA32 __builtin_amdgcn_mfma_f32_32x32x16_bf16

// ws layout:
//   float [0..63] bq' (×0.125), [64..127] ecv
//   ushort base wsu = (ushort*)(ws+128):
//     [0..4095]      Aq (×0.125) row-major [dout][din]
//     [4096..8191]   Ak row-major
//     [8192..12287]  Av row-major
//     [12288 ..)     Kg[bh][key][dout]   (64*2048*64)
//     [+8388608 ..)  Vtg[bh][dout][key]  (64*64*2048)
#define KG_OFF  12288
#define VG_OFF  (12288 + 8388608)
#define WS_NEED ((size_t)512 + 2ull * (12288 + 2ull * 8388608))

__device__ __forceinline__ unsigned short f2bf(float f) {
    unsigned int v = __float_as_uint(f);
    unsigned int r = v + 0x7FFFu + ((v >> 16) & 1u);
    return (unsigned short)(r >> 16);
}
__device__ __forceinline__ unsigned int pk2r(float a, float b) {
    return __builtin_amdgcn_perm(__float_as_uint(b) + 0x8000u,
                                 __float_as_uint(a) + 0x8000u, 0x07060302u);
}
__device__ __forceinline__ unsigned int pk2t(float a, float b) {
    return __builtin_amdgcn_perm(__float_as_uint(b), __float_as_uint(a), 0x07060302u);
}
__device__ __forceinline__ f32x16 z16() {
    f32x16 v;
    #pragma unroll
    for (int i = 0; i < 16; i++) v[i] = 0.f;
    return v;
}

// acc[0..16) = (row · L)[i0..i0+16)
__device__ __forceinline__ void mm16(const float* __restrict__ wrow,
                                     const float* __restrict__ L, int i0,
                                     float* __restrict__ acc) {
    #pragma unroll
    for (int ii = 0; ii < 16; ii++) acc[ii] = 0.f;
    for (int t = 0; t < 64; t += 4) {
        float4 w4 = *(const float4*)(wrow + t);
        #pragma unroll
        for (int d = 0; d < 4; d++) {
            float wv = (d == 0) ? w4.x : (d == 1) ? w4.y : (d == 2) ? w4.z : w4.w;
            const float* lr = L + (t + d) * 64 + i0;
            float4 a = *(const float4*)lr;
            float4 b = *(const float4*)(lr + 4);
            float4 c = *(const float4*)(lr + 8);
            float4 e = *(const float4*)(lr + 12);
            acc[0] += wv * a.x;  acc[1] += wv * a.y;  acc[2]  += wv * a.z;  acc[3]  += wv * a.w;
            acc[4] += wv * b.x;  acc[5] += wv * b.y;  acc[6]  += wv * b.z;  acc[7]  += wv * b.w;
            acc[8] += wv * c.x;  acc[9] += wv * c.y;  acc[10] += wv * c.z;  acc[11] += wv * c.w;
            acc[12] += wv * e.x; acc[13] += wv * e.y; acc[14] += wv * e.z;  acc[15] += wv * e.w;
        }
    }
}

// ---------------- weight folding (unchanged from R3) ----------------
__global__ __launch_bounds__(256)
void qmt_combine(const float* __restrict__ Wi,  const float* __restrict__ bi,
                 const float* __restrict__ Wq,  const float* __restrict__ bq,
                 const float* __restrict__ Wk,  const float* __restrict__ bk,
                 const float* __restrict__ Wv,  const float* __restrict__ bv,
                 const float* __restrict__ Wc,  const float* __restrict__ bc,
                 const float* __restrict__ Wci, const float* __restrict__ bci,
                 const float* __restrict__ Wm,  const float* __restrict__ bm,
                 const float* __restrict__ Wmi, const float* __restrict__ bmi,
                 float* __restrict__ ws) {
    const int tid = threadIdx.x;
    const int o = tid & 63;
    const int i0 = (tid >> 6) * 16;
    const bool lead = (tid < 64);

    __shared__ float Wi_s[64 * 64];
    __shared__ float Wvi_s[64 * 64];
    __shared__ float M_s[64 * 64];
    __shared__ float bi_s[64], bvi_s[64], c1[64], c2[4];
    __shared__ float U1[32], U2[4 * 64];

    unsigned short* wsu = (unsigned short*)(ws + 128);

    for (int idx = tid; idx < 4096; idx += 256) Wi_s[idx] = Wi[idx];
    if (lead) bi_s[o] = bi[o];
    __syncthreads();

    float acc[16];
    mm16(Wq + o * 64, Wi_s, i0, acc);
    #pragma unroll
    for (int ii = 0; ii < 16; ii++) wsu[o * 64 + i0 + ii] = f2bf(acc[ii] * 0.125f);
    if (lead) {
        float s = bq[o];
        for (int t = 0; t < 64; t++) s += Wq[o * 64 + t] * bi_s[t];
        ws[o] = s * 0.125f;
    }
    mm16(Wk + o * 64, Wi_s, i0, acc);
    #pragma unroll
    for (int ii = 0; ii < 16; ii++) wsu[4096 + o * 64 + i0 + ii] = f2bf(acc[ii]);
    mm16(Wv + o * 64, Wi_s, i0, acc);
    #pragma unroll
    for (int ii = 0; ii < 16; ii++) Wvi_s[o * 64 + i0 + ii] = acc[ii];
    if (lead) {
        float s = bv[o];
        for (int t = 0; t < 64; t++) s += Wv[o * 64 + t] * bi_s[t];
        bvi_s[o] = s;
    }
    if (tid < 32) {
        int a = tid >> 3, c = tid & 7;
        float s = 0.f;
        for (int t = 0; t < 64; t++) s += Wm[a * 64 + t] * Wci[t * 8 + c];
        U1[a * 8 + c] = s;
    }
    __syncthreads();
    if (lead) {
        for (int a = 0; a < 4; a++) {
            float s = 0.f;
            for (int cc = 0; cc < 8; cc++) s += U1[a * 8 + cc] * Wc[cc * 64 + o];
            U2[a * 64 + o] = s;
        }
        float s = bci[o];
        for (int j = 0; j < 8; j++) s += Wci[o * 8 + j] * bc[j];
        c1[o] = s;
    }
    __syncthreads();
    #pragma unroll
    for (int ii = 0; ii < 16; ii++) {
        float s = 0.f;
        for (int a = 0; a < 4; a++) s += Wmi[o * 4 + a] * U2[a * 64 + i0 + ii];
        M_s[o * 64 + i0 + ii] = s;
    }
    if (tid < 4) {
        float s = bm[tid];
        for (int i = 0; i < 64; i++) s += Wm[tid * 64 + i] * c1[i];
        c2[tid] = s;
    }
    __syncthreads();
    mm16(M_s + o * 64, Wvi_s, i0, acc);
    #pragma unroll
    for (int ii = 0; ii < 16; ii++) wsu[8192 + o * 64 + i0 + ii] = f2bf(acc[ii]);
    if (lead) {
        float bvv = 0.f;
        for (int t = 0; t < 64; t++) bvv += M_s[o * 64 + t] * bvi_s[t];
        float cvv = bmi[o];
        for (int a = 0; a < 4; a++) cvv += Wmi[o * 4 + a] * c2[a];
        ws[64 + o] = cvv + bvv;
    }
}

// ---------------- KV prepass: grid (32 ktiles, 64 bh), 256 thr ----------------
__global__ __launch_bounds__(256)
void qmt_kv(const float* __restrict__ x, float* __restrict__ ws) {
    const int tid = threadIdx.x;
    const int w = tid >> 6;
    const int lane = tid & 63;
    const int ln = lane & 31;
    const int h = lane >> 5;
    const int kt = blockIdx.x;
    const int b = blockIdx.y >> 4;
    const int hh = blockIdx.y & 15;

    const unsigned short* wsu = (const unsigned short*)(ws + 128);
    unsigned short* Kg = (unsigned short*)(ws + 128) + KG_OFF + (size_t)blockIdx.y * (2048 * 64);
    unsigned short* Vg = (unsigned short*)(ws + 128) + VG_OFF + (size_t)blockIdx.y * (64 * 2048);

    const int krl = (w >> 1) * 32 + ln;
    const int dt32 = (w & 1) * 32;

    bf16x8 akf[4], avf[4];
    #pragma unroll
    for (int c = 0; c < 4; c++) {
        int row = dt32 + ln;
        int col = c * 16 + h * 8;
        akf[c] = *(const bf16x8*)(wsu + 4096 + row * 64 + col);
        avf[c] = *(const bf16x8*)(wsu + 8192 + row * 64 + col);
    }
    bf16x8 xf[4];
    const float* xr = x + ((size_t)(b * SEQ + kt * 64 + krl) * DM + hh * HD);
    #pragma unroll
    for (int c = 0; c < 4; c++) {
        const float* p = xr + c * 16 + h * 8;
        float4 f0 = *(const float4*)p;
        float4 f1 = *(const float4*)(p + 4);
        union { bf16x8 v; unsigned int u[4]; } t;
        t.u[0] = pk2t(f0.x, f0.y); t.u[1] = pk2t(f0.z, f0.w);
        t.u[2] = pk2t(f1.x, f1.y); t.u[3] = pk2t(f1.z, f1.w);
        xf[c] = t.v;
    }
    f32x16 kacc = z16(), vacc = z16();
    #pragma unroll
    for (int c = 0; c < 4; c++) kacc = MFMA32(akf[c], xf[c], kacc, 0, 0, 0);
    #pragma unroll
    for (int c = 0; c < 4; c++) vacc = MFMA32(xf[c], avf[c], vacc, 0, 0, 0);
    #pragma unroll
    for (int g = 0; g < 4; g++) {
        uint2 pk_, pv_;
        pk_.x = pk2r(kacc[4 * g + 0], kacc[4 * g + 1]);
        pk_.y = pk2r(kacc[4 * g + 2], kacc[4 * g + 3]);
        *(uint2*)&Kg[(size_t)(kt * 64 + krl) * 64 + dt32 + 8 * g + 4 * h] = pk_;
        pv_.x = pk2r(vacc[4 * g + 0], vacc[4 * g + 1]);
        pv_.y = pk2r(vacc[4 * g + 2], vacc[4 * g + 3]);
        *(uint2*)&Vg[(size_t)(dt32 + ln) * 2048 + kt * 64 + (w >> 1) * 32 + 8 * g + 4 * h] = pv_;
    }
}

// ---------------- MFMA flash attention, double-buffered ----------------
// grid (16 q-tiles, 64 bh), block 256 = 4 waves. QT=128, KT=64, 1 barrier/iter.
__global__ __launch_bounds__(256, 2)
void qmt_attn2(const float* __restrict__ x, const float* __restrict__ wsf,
               float* __restrict__ out) {
    __shared__ __align__(16) unsigned short ps_s[128 * 72];     // Q pack (prologue) then P; wave-local rows
    __shared__ __align__(16) unsigned short ks_s[2][64 * 72];   // K [key][dout], double-buffered
    __shared__ __align__(16) unsigned short vt_s[2][64 * 72];   // V^T [dout][key], double-buffered
    __shared__ float als_l[128];
    __shared__ float ls_l[128];

    const int tid = threadIdx.x;
    const int w = tid >> 6;
    const int lane = tid & 63;
    const int ln = lane & 31;
    const int h = lane >> 5;
    const int b = blockIdx.y >> 4;
    const int hh = blockIdx.y & 15;
    const int qbase = blockIdx.x * 128;

    const unsigned short* wsu = (const unsigned short*)(wsf + 128);
    const unsigned short* Kg = wsu + KG_OFF + (size_t)blockIdx.y * (2048 * 64);
    const unsigned short* Vg = wsu + VG_OFF + (size_t)blockIdx.y * (64 * 2048);

    const float ec0 = wsf[64 + ln];
    const float ec1 = wsf[96 + ln];

    // ---- Q projection: Q^T = Aq·x^T, pack to ps_s[qrow][dout], reload B-frags ----
    bf16x8 qf[4];
    {
        bf16x8 xq[4];
        const float* xrow = x + ((size_t)(b * SEQ + qbase + w * 32 + ln) * DM + hh * HD);
        #pragma unroll
        for (int c = 0; c < 4; c++) {
            const float* p = xrow + c * 16 + h * 8;
            float4 f0 = *(const float4*)p;
            float4 f1 = *(const float4*)(p + 4);
            union { bf16x8 v; unsigned int u[4]; } t;
            t.u[0] = pk2t(f0.x, f0.y); t.u[1] = pk2t(f0.z, f0.w);
            t.u[2] = pk2t(f1.x, f1.y); t.u[3] = pk2t(f1.z, f1.w);
            xq[c] = t.v;
        }
        #pragma unroll
        for (int m = 0; m < 2; m++) {
            f32x16 acc;
            #pragma unroll
            for (int g = 0; g < 4; g++) {
                float4 b4 = *(const float4*)&wsf[m * 32 + 8 * g + 4 * h];
                acc[4 * g + 0] = b4.x; acc[4 * g + 1] = b4.y;
                acc[4 * g + 2] = b4.z; acc[4 * g + 3] = b4.w;
            }
            #pragma unroll
            for (int c = 0; c < 4; c++) {
                bf16x8 aq = *(const bf16x8*)(wsu + (m * 32 + ln) * 64 + c * 16 + h * 8);
                acc = MFMA32(aq, xq[c], acc, 0, 0, 0);
            }
            #pragma unroll
            for (int g = 0; g < 4; g++) {
                uint2 pw;
                pw.x = pk2r(acc[4 * g + 0], acc[4 * g + 1]);
                pw.y = pk2r(acc[4 * g + 2], acc[4 * g + 3]);
                *(uint2*)&ps_s[(w * 32 + ln) * 72 + m * 32 + 8 * g + 4 * h] = pw;
            }
        }
        #pragma unroll
        for (int c = 0; c < 4; c++)
            qf[c] = *(const bf16x8*)&ps_s[(w * 32 + ln) * 72 + c * 16 + h * 8];
    }

    f32x16 o0 = z16(), o1 = z16();
    float m_i = -1e30f, l_i = 0.f;

    // staging: thread handles rows (srow, srow+32), 16B column chunk scol
    const int srow = tid >> 3;
    const int scol = (tid & 7) * 8;

    u16x8 ka, kb, va, vb;
    ka = *(const u16x8*)(Kg + (size_t)srow * 64 + scol);
    kb = *(const u16x8*)(Kg + (size_t)(srow + 32) * 64 + scol);
    va = *(const u16x8*)(Vg + (size_t)srow * 2048 + scol);
    vb = *(const u16x8*)(Vg + (size_t)(srow + 32) * 2048 + scol);
    *(u16x8*)&ks_s[0][srow * 72 + scol] = ka;
    *(u16x8*)&ks_s[0][(srow + 32) * 72 + scol] = kb;
    *(u16x8*)&vt_s[0][srow * 72 + scol] = va;
    *(u16x8*)&vt_s[0][(srow + 32) * 72 + scol] = vb;
    __syncthreads();

    for (int kt = 0; kt < SEQ / 64; kt++) {
        const int cur = kt & 1;
        if (kt < SEQ / 64 - 1) {  // issue next tile's global loads early
            const int kn = (kt + 1) * 64;
            ka = *(const u16x8*)(Kg + (size_t)(kn + srow) * 64 + scol);
            kb = *(const u16x8*)(Kg + (size_t)(kn + srow + 32) * 64 + scol);
            va = *(const u16x8*)(Vg + (size_t)srow * 2048 + kn + scol);
            vb = *(const u16x8*)(Vg + (size_t)(srow + 32) * 2048 + kn + scol);
        }

        // ---- S^T = K·Q^T + online softmax ----
        f32x16 st0 = z16(), st1 = z16();
        #pragma unroll
        for (int c = 0; c < 4; c++) {
            bf16x8 k0 = *(const bf16x8*)&ks_s[cur][ln * 72 + c * 16 + h * 8];
            bf16x8 k1 = *(const bf16x8*)&ks_s[cur][(32 + ln) * 72 + c * 16 + h * 8];
            st0 = MFMA32(k0, qf[c], st0, 0, 0, 0);
            st1 = MFMA32(k1, qf[c], st1, 0, 0, 0);
        }
        float mx = st0[0];
        #pragma unroll
        for (int i = 1; i < 16; i++) mx = fmaxf(mx, st0[i]);
        #pragma unroll
        for (int i = 0; i < 16; i++) mx = fmaxf(mx, st1[i]);
        mx = fmaxf(mx, __shfl_xor(mx, 32));
        const float mn = fmaxf(m_i, mx);
        const float al = __expf(m_i - mn);
        float ss = 0.f;
        #pragma unroll
        for (int i = 0; i < 16; i++) { st0[i] = __expf(st0[i] - mn); ss += st0[i]; }
        #pragma unroll
        for (int i = 0; i < 16; i++) { st1[i] = __expf(st1[i] - mn); ss += st1[i]; }
        ss += __shfl_xor(ss, 32);
        l_i = l_i * al + ss;
        m_i = mn;
        if (lane < 32) als_l[w * 32 + lane] = al;
        #pragma unroll
        for (int g = 0; g < 4; g++) {
            uint2 p0, p1;
            p0.x = pk2r(st0[4 * g + 0], st0[4 * g + 1]);
            p0.y = pk2r(st0[4 * g + 2], st0[4 * g + 3]);
            *(uint2*)&ps_s[(w * 32 + ln) * 72 + 8 * g + 4 * h] = p0;
            p1.x = pk2r(st1[4 * g + 0], st1[4 * g + 1]);
            p1.y = pk2r(st1[4 * g + 2], st1[4 * g + 3]);
            *(uint2*)&ps_s[(w * 32 + ln) * 72 + 32 + 8 * g + 4 * h] = p1;
        }
        #pragma unroll
        for (int g = 0; g < 4; g++) {
            float4 a4 = *(const float4*)&als_l[w * 32 + 8 * g + 4 * h];
            o0[4 * g + 0] *= a4.x; o0[4 * g + 1] *= a4.y;
            o0[4 * g + 2] *= a4.z; o0[4 * g + 3] *= a4.w;
            o1[4 * g + 0] *= a4.x; o1[4 * g + 1] *= a4.y;
            o1[4 * g + 2] *= a4.z; o1[4 * g + 3] *= a4.w;
        }
        // ---- O += P·V ----
        #pragma unroll
        for (int c = 0; c < 4; c++) {
            bf16x8 pf = *(const bf16x8*)&ps_s[(w * 32 + ln) * 72 + c * 16 + h * 8];
            bf16x8 v0 = *(const bf16x8*)&vt_s[cur][ln * 72 + c * 16 + h * 8];
            bf16x8 v1 = *(const bf16x8*)&vt_s[cur][(32 + ln) * 72 + c * 16 + h * 8];
            o0 = MFMA32(pf, v0, o0, 0, 0, 0);
            o1 = MFMA32(pf, v1, o1, 0, 0, 0);
        }
        if (kt < SEQ / 64 - 1) {  // write next tile into the other buffer
            *(u16x8*)&ks_s[1 - cur][srow * 72 + scol] = ka;
            *(u16x8*)&ks_s[1 - cur][(srow + 32) * 72 + scol] = kb;
            *(u16x8*)&vt_s[1 - cur][srow * 72 + scol] = va;
            *(u16x8*)&vt_s[1 - cur][(srow + 32) * 72 + scol] = vb;
        }
        __syncthreads();
    }

    // ---- epilogue ----
    if (lane < 32) ls_l[w * 32 + lane] = l_i;
    #pragma unroll
    for (int g = 0; g < 4; g++) {
        float4 l4 = *(const float4*)&ls_l[w * 32 + 8 * g + 4 * h];
        float4 iv = make_float4(1.f / l4.x, 1.f / l4.y, 1.f / l4.z, 1.f / l4.w);
        #pragma unroll
        for (int i = 0; i < 4; i++) {
            float ivv = (i == 0) ? iv.x : (i == 1) ? iv.y : (i == 2) ? iv.z : iv.w;
            int q = qbase + w * 32 + 8 * g + 4 * h + i;
            float* orow = out + ((size_t)(b * SEQ + q) * DM + hh * HD);
            orow[ln] = o0[4 * g + i] * ivv + ec0;
            orow[32 + ln] = o1[4 * g + i] * ivv + ec1;
        }
    }
}

// ---------------- R3 fallback attention (in-loop KV projection) ----------------
__global__ __launch_bounds__(256, 3)
void qmt_attn_fb(const float* __restrict__ x, const float* __restrict__ wsf,
                 float* __restrict__ out) {
    __shared__ __align__(16) unsigned short ps_s[128 * 72];
    __shared__ __align__(16) unsigned short ks_s[64 * 72];
    __shared__ __align__(16) unsigned short vt_s[64 * 72];
    __shared__ float als_l[128];
    __shared__ float ls_l[128];

    const int tid = threadIdx.x;
    const int w = tid >> 6;
    const int lane = tid & 63;
    const int ln = lane & 31;
    const int h = lane >> 5;
    const int b = blockIdx.y >> 4;
    const int hh = blockIdx.y & 15;
    const int qbase = blockIdx.x * 128;

    const unsigned short* wsu = (const unsigned short*)(wsf + 128);

    bf16x8 akf[4], avf[4];
    #pragma unroll
    for (int c = 0; c < 4; c++) {
        int row = (w & 1) * 32 + ln;
        int col = c * 16 + h * 8;
        akf[c] = *(const bf16x8*)(wsu + 4096 + row * 64 + col);
        avf[c] = *(const bf16x8*)(wsu + 8192 + row * 64 + col);
    }
    const float ec0 = wsf[64 + ln];
    const float ec1 = wsf[96 + ln];

    bf16x8 qf[4];
    {
        bf16x8 xq[4];
        const float* xrow = x + ((size_t)(b * SEQ + qbase + w * 32 + ln) * DM + hh * HD);
        #pragma unroll
        for (int c = 0; c < 4; c++) {
            const float* p = xrow + c * 16 + h * 8;
            float4 f0 = *(const float4*)p;
            float4 f1 = *(const float4*)(p + 4);
            union { bf16x8 v; unsigned int u[4]; } t;
            t.u[0] = pk2t(f0.x, f0.y); t.u[1] = pk2t(f0.z, f0.w);
            t.u[2] = pk2t(f1.x, f1.y); t.u[3] = pk2t(f1.z, f1.w);
            xq[c] = t.v;
        }
        #pragma unroll
        for (int m = 0; m < 2; m++) {
            f32x16 acc;
            #pragma unroll
            for (int g = 0; g < 4; g++) {
                float4 b4 = *(const float4*)&wsf[m * 32 + 8 * g + 4 * h];
                acc[4 * g + 0] = b4.x; acc[4 * g + 1] = b4.y;
                acc[4 * g + 2] = b4.z; acc[4 * g + 3] = b4.w;
            }
            #pragma unroll
            for (int c = 0; c < 4; c++) {
                bf16x8 aq = *(const bf16x8*)(wsu + (m * 32 + ln) * 64 + c * 16 + h * 8);
                acc = MFMA32(aq, xq[c], acc, 0, 0, 0);
            }
            #pragma unroll
            for (int g = 0; g < 4; g++) {
                uint2 pw;
                pw.x = pk2r(acc[4 * g + 0], acc[4 * g + 1]);
                pw.y = pk2r(acc[4 * g + 2], acc[4 * g + 3]);
                *(uint2*)&ps_s[(w * 32 + ln) * 72 + m * 32 + 8 * g + 4 * h] = pw;
            }
        }
        #pragma unroll
        for (int c = 0; c < 4; c++)
            qf[c] = *(const bf16x8*)&ps_s[(w * 32 + ln) * 72 + c * 16 + h * 8];
    }

    f32x16 o0 = z16(), o1 = z16();
    float m_i = -1e30f, l_i = 0.f;

    const int krl = (w >> 1) * 32 + ln;
    const int dt32 = (w & 1) * 32;

    for (int kt = 0; kt < SEQ / 64; kt++) {
        bf16x8 xf[4];
        const float* xr = x + ((size_t)(b * SEQ + kt * 64 + krl) * DM + hh * HD);
        #pragma unroll
        for (int c = 0; c < 4; c++) {
            const float* p = xr + c * 16 + h * 8;
            float4 f0 = *(const float4*)p;
            float4 f1 = *(const float4*)(p + 4);
            union { bf16x8 v; unsigned int u[4]; } t;
            t.u[0] = pk2t(f0.x, f0.y); t.u[1] = pk2t(f0.z, f0.w);
            t.u[2] = pk2t(f1.x, f1.y); t.u[3] = pk2t(f1.z, f1.w);
            xf[c] = t.v;
        }
        f32x16 kacc = z16(), vacc = z16();
        #pragma unroll
        for (int c = 0; c < 4; c++) kacc = MFMA32(akf[c], xf[c], kacc, 0, 0, 0);
        #pragma unroll
        for (int c = 0; c < 4; c++) vacc = MFMA32(xf[c], avf[c], vacc, 0, 0, 0);
        #pragma unroll
        for (int g = 0; g < 4; g++) {
            uint2 pk_, pv_;
            pk_.x = pk2r(kacc[4 * g + 0], kacc[4 * g + 1]);
            pk_.y = pk2r(kacc[4 * g + 2], kacc[4 * g + 3]);
            *(uint2*)&ks_s[krl * 72 + dt32 + 8 * g + 4 * h] = pk_;
            pv_.x = pk2r(vacc[4 * g + 0], vacc[4 * g + 1]);
            pv_.y = pk2r(vacc[4 * g + 2], vacc[4 * g + 3]);
            *(uint2*)&vt_s[(dt32 + ln) * 72 + (w >> 1) * 32 + 8 * g + 4 * h] = pv_;
        }
        __syncthreads();

        f32x16 st0 = z16(), st1 = z16();
        #pragma unroll
        for (int c = 0; c < 4; c++) {
            bf16x8 k0 = *(const bf16x8*)&ks_s[ln * 72 + c * 16 + h * 8];
            bf16x8 k1 = *(const bf16x8*)&ks_s[(32 + ln) * 72 + c * 16 + h * 8];
            st0 = MFMA32(k0, qf[c], st0, 0, 0, 0);
            st1 = MFMA32(k1, qf[c], st1, 0, 0, 0);
        }
        float mx = st0[0];
        #pragma unroll
        for (int i = 1; i < 16; i++) mx = fmaxf(mx, st0[i]);
        #pragma unroll
        for (int i = 0; i < 16; i++) mx = fmaxf(mx, st1[i]);
        mx = fmaxf(mx, __shfl_xor(mx, 32));
        const float mn = fmaxf(m_i, mx);
        const float al = __expf(m_i - mn);
        float ss = 0.f;
        #pragma unroll
        for (int i = 0; i < 16; i++) { st0[i] = __expf(st0[i] - mn); ss += st0[i]; }
        #pragma unroll
        for (int i = 0; i < 16; i++) { st1[i] = __expf(st1[i] - mn); ss += st1[i]; }
        ss += __shfl_xor(ss, 32);
        l_i = l_i * al + ss;
        m_i = mn;
        if (lane < 32) als_l[w * 32 + lane] = al;
        #pragma unroll
        for (int g = 0; g < 4; g++) {
            uint2 p0, p1;
            p0.x = pk2r(st0[4 * g + 0], st0[4 * g + 1]);
            p0.y = pk2r(st0[4 * g + 2], st0[4 * g + 3]);
            *(uint2*)&ps_s[(w * 32 + ln) * 72 + 8 * g + 4 * h] = p0;
            p1.x = pk2r(st1[4 * g + 0], st1[4 * g + 1]);
            p1.y = pk2r(st1[4 * g + 2], st1[4 * g + 3]);
            *(uint2*)&ps_s[(w * 32 + ln) * 72 + 32 + 8 * g + 4 * h] = p1;
        }
        #pragma unroll
        for (int g = 0; g < 4; g++) {
            float4 a4 = *(const float4*)&als_l[w * 32 + 8 * g + 4 * h];
            o0[4 * g + 0] *= a4.x; o0[4 * g + 1] *= a4.y;
            o0[4 * g + 2] *= a4.z; o0[4 * g + 3] *= a4.w;
            o1[4 * g + 0] *= a4.x; o1[4 * g + 1] *= a4.y;
            o1[4 * g + 2] *= a4.z; o1[4 * g + 3] *= a4.w;
        }
        #pragma unroll
        for (int c = 0; c < 4; c++) {
            bf16x8 pf = *(const bf16x8*)&ps_s[(w * 32 + ln) * 72 + c * 16 + h * 8];
            bf16x8 v0 = *(const bf16x8*)&vt_s[ln * 72 + c * 16 + h * 8];
            bf16x8 v1 = *(const bf16x8*)&vt_s[(32 + ln) * 72 + c * 16 + h * 8];
            o0 = MFMA32(pf, v0, o0, 0, 0, 0);
            o1 = MFMA32(pf, v1, o1, 0, 0, 0);
        }
        __syncthreads();
    }

    if (lane < 32) ls_l[w * 32 + lane] = l_i;
    #pragma unroll
    for (int g = 0; g < 4; g++) {
        float4 l4 = *(const float4*)&ls_l[w * 32 + 8 * g + 4 * h];
        float4 iv = make_float4(1.f / l4.x, 1.f / l4.y, 1.f / l4.z, 1.f / l4.w);
        #pragma unroll
        for (int i = 0; i < 4; i++) {
            float ivv = (i == 0) ? iv.x : (i == 1) ? iv.y : (i == 2) ? iv.z : iv.w;
            int q = qbase + w * 32 + 8 * g + 4 * h + i;
            float* orow = out + ((size_t)(b * SEQ + q) * DM + hh * HD);
            orow[ln] = o0[4 * g + i] * ivv + ec0;
            orow[32 + ln] = o1[4 * g + i] * ivv + ec1;
        }
    }
}

extern "C" void kernel_launch(void* const* d_in, const int* in_sizes, int n_in,
                              void* d_out, int out_size, void* d_ws, size_t ws_size,
                              hipStream_t stream) {
    const float* x = (const float*)d_in[0];
    float* wsf = (float*)d_ws;

    qmt_combine<<<1, 256, 0, stream>>>(
        (const float*)d_in[1],  (const float*)d_in[2],
        (const float*)d_in[3],  (const float*)d_in[4],
        (const float*)d_in[5],  (const float*)d_in[6],
        (const float*)d_in[7],  (const float*)d_in[8],
        (const float*)d_in[9],  (const float*)d_in[10],
        (const float*)d_in[11], (const float*)d_in[12],
        (const float*)d_in[13], (const float*)d_in[14],
        (const float*)d_in[15], (const float*)d_in[16],
        wsf);

    if (ws_size >= WS_NEED) {
        dim3 gkv(SEQ / 64, 64);
        qmt_kv<<<gkv, 256, 0, stream>>>(x, wsf);
        dim3 grid(SEQ / 128, 64);
        qmt_attn2<<<grid, 256, 0, stream>>>(x, wsf, (float*)d_out);
    } else {
        dim3 grid(SEQ / 128, 64);
        qmt_attn_fb<<<grid, 256, 0, stream>>>(x, wsf, (float*)d_out);
    }
}

// Round 5
// 246.042 us; speedup vs baseline: 13.6296x; 1.0759x over previous
//
#include <hip/hip_runtime.h>

// QuantumMotivicTile — B=4, S=2048, H=16, hd=64, D=1024, fp32 I/O.
// final = softmax(q k^T / 8) @ v'' + ecv
//   Aq = QS·Wq·Wi (QS = 0.125·log2e → scores in log2 domain, exp2 softmax),
//   Ak = Wk·Wi (bias cancels in softmax), Av = M·Wv·Wi, M = Wmi·Wm·Wci·Wc,
//   ecv = M·(Wv·bi+bv) + cvec.
// R5: combine reads all weights via LDS (kills serial cold-HBM lead loops);
// kv prepass 4 tiles/block; attn single-buffer + reg-prefetch, 4 blocks/CU.

#define SEQ 2048
#define DM  1024
#define HD  64
#define QS  0.180336880111120429f  // 0.125 * log2(e)

typedef short bf16x8 __attribute__((ext_vector_type(8)));
typedef unsigned short u16x8 __attribute__((ext_vector_type(8)));
typedef float f32x16 __attribute__((ext_vector_type(16)));

#define MFMA32 __builtin_amdgcn_mfma_f32_32x32x16_bf16

#if defined(__has_builtin)
#if __has_builtin(__builtin_amdgcn_exp2f)
#define EXP2(x) __builtin_amdgcn_exp2f(x)
#endif
#endif
#ifndef EXP2
#define EXP2(x) exp2f(x)
#endif

// ws layout:
//   float [0..63] bq' (×QS), [64..127] ecv
//   ushort base wsu = (ushort*)(ws+128):
//     [0..4095]      Aq (×QS) row-major [dout][din]
//     [4096..8191]   Ak row-major
//     [8192..12287]  Av row-major
//     [12288 ..)     Kg[bh][key][dout]   (64*2048*64)
//     [+8388608 ..)  Vtg[bh][dout][key]  (64*64*2048)
#define KG_OFF  12288
#define VG_OFF  (12288 + 8388608)
#define WS_NEED ((size_t)512 + 2ull * (12288 + 2ull * 8388608))

__device__ __forceinline__ unsigned short f2bf(float f) {
    unsigned int v = __float_as_uint(f);
    unsigned int r = v + 0x7FFFu + ((v >> 16) & 1u);
    return (unsigned short)(r >> 16);
}
__device__ __forceinline__ unsigned int pk2r(float a, float b) {
    return __builtin_amdgcn_perm(__float_as_uint(b) + 0x8000u,
                                 __float_as_uint(a) + 0x8000u, 0x07060302u);
}
__device__ __forceinline__ unsigned int pk2t(float a, float b) {
    return __builtin_amdgcn_perm(__float_as_uint(b), __float_as_uint(a), 0x07060302u);
}
__device__ __forceinline__ f32x16 z16() {
    f32x16 v;
    #pragma unroll
    for (int i = 0; i < 16; i++) v[i] = 0.f;
    return v;
}

// acc[0..16) = (wrow · L)[i0..i0+16); wrow/L in LDS, row stride 68 floats
__device__ __forceinline__ void mm16L(const float* __restrict__ wrow,
                                      const float* __restrict__ L, int i0,
                                      float* __restrict__ acc) {
    #pragma unroll
    for (int ii = 0; ii < 16; ii++) acc[ii] = 0.f;
    for (int t = 0; t < 64; t += 4) {
        float4 w4 = *(const float4*)(wrow + t);
        #pragma unroll
        for (int d = 0; d < 4; d++) {
            float wv = (d == 0) ? w4.x : (d == 1) ? w4.y : (d == 2) ? w4.z : w4.w;
            const float* lr = L + (t + d) * 68 + i0;
            float4 a = *(const float4*)lr;
            float4 b = *(const float4*)(lr + 4);
            float4 c = *(const float4*)(lr + 8);
            float4 e = *(const float4*)(lr + 12);
            acc[0] += wv * a.x;  acc[1] += wv * a.y;  acc[2]  += wv * a.z;  acc[3]  += wv * a.w;
            acc[4] += wv * b.x;  acc[5] += wv * b.y;  acc[6]  += wv * b.z;  acc[7]  += wv * b.w;
            acc[8] += wv * c.x;  acc[9] += wv * c.y;  acc[10] += wv * c.z;  acc[11] += wv * c.w;
            acc[12] += wv * e.x; acc[13] += wv * e.y; acc[14] += wv * e.z;  acc[15] += wv * e.w;
        }
    }
}

// ---------------- weight folding (1 block, 256 threads, all-LDS) ----------------
__global__ __launch_bounds__(256)
void qmt_combine(const float* __restrict__ Wi,  const float* __restrict__ bi,
                 const float* __restrict__ Wq,  const float* __restrict__ bq,
                 const float* __restrict__ Wk,  const float* __restrict__ bk,
                 const float* __restrict__ Wv,  const float* __restrict__ bv,
                 const float* __restrict__ Wc,  const float* __restrict__ bc,
                 const float* __restrict__ Wci, const float* __restrict__ bci,
                 const float* __restrict__ Wm,  const float* __restrict__ bm,
                 const float* __restrict__ Wmi, const float* __restrict__ bmi,
                 float* __restrict__ ws) {
    const int tid = threadIdx.x;
    const int o = tid & 63;
    const int i0 = (tid >> 6) * 16;
    const bool lead = (tid < 64);

    __shared__ float Wi_s[64 * 68];
    __shared__ float Wq_s[64 * 68];
    __shared__ float Wk_s[64 * 68];
    __shared__ float Wv_s[64 * 68];
    __shared__ float Wvi_s[64 * 68];
    __shared__ float M_s[64 * 68];
    __shared__ float Wc_s[512];    // 8x64
    __shared__ float Wci_s[512];   // 64x8
    __shared__ float Wm_s[256];    // 4x64
    __shared__ float Wmi_s[256];   // 64x4
    __shared__ float bi_s[64], bvi_s[64], c1[64], c2[4];
    __shared__ float U1[32], U2[256];

    unsigned short* wsu = (unsigned short*)(ws + 128);

    // coalesced float4 staging of all weight matrices
    for (int i4 = tid; i4 < 1024; i4 += 256) {
        int r = i4 >> 4, c = (i4 & 15) * 4;
        *(float4*)&Wi_s[r * 68 + c] = *(const float4*)(Wi + i4 * 4);
        *(float4*)&Wq_s[r * 68 + c] = *(const float4*)(Wq + i4 * 4);
        *(float4*)&Wk_s[r * 68 + c] = *(const float4*)(Wk + i4 * 4);
        *(float4*)&Wv_s[r * 68 + c] = *(const float4*)(Wv + i4 * 4);
    }
    if (tid < 128) {
        *(float4*)&Wc_s[tid * 4]  = *(const float4*)(Wc + tid * 4);
        *(float4*)&Wci_s[tid * 4] = *(const float4*)(Wci + tid * 4);
    } else if (tid < 192) {
        int t = tid - 128;
        *(float4*)&Wm_s[t * 4]  = *(const float4*)(Wm + t * 4);
        *(float4*)&Wmi_s[t * 4] = *(const float4*)(Wmi + t * 4);
    }
    if (lead) bi_s[o] = bi[o];
    __syncthreads();  // (1)

    float acc[16];
    // Aq = QS·Wq·Wi
    mm16L(Wq_s + o * 68, Wi_s, i0, acc);
    #pragma unroll
    for (int ii = 0; ii < 16; ii++) wsu[o * 64 + i0 + ii] = f2bf(acc[ii] * QS);
    if (lead) {
        float s = bq[o];
        for (int t = 0; t < 64; t++) s += Wq_s[o * 68 + t] * bi_s[t];
        ws[o] = s * QS;
    }
    // Ak = Wk·Wi
    mm16L(Wk_s + o * 68, Wi_s, i0, acc);
    #pragma unroll
    for (int ii = 0; ii < 16; ii++) wsu[4096 + o * 64 + i0 + ii] = f2bf(acc[ii]);
    // Wvi = Wv·Wi, bvi
    mm16L(Wv_s + o * 68, Wi_s, i0, acc);
    #pragma unroll
    for (int ii = 0; ii < 16; ii++) Wvi_s[o * 68 + i0 + ii] = acc[ii];
    if (lead) {
        float s = bv[o];
        for (int t = 0; t < 64; t++) s += Wv_s[o * 68 + t] * bi_s[t];
        bvi_s[o] = s;
    }
    // U1 = Wm·Wci (4x8)
    if (tid < 32) {
        int a = tid >> 3, c = tid & 7;
        float s = 0.f;
        for (int t = 0; t < 64; t++) s += Wm_s[a * 64 + t] * Wci_s[t * 8 + c];
        U1[a * 8 + c] = s;
    }
    __syncthreads();  // (2)
    if (lead) {
        for (int a = 0; a < 4; a++) {
            float s = 0.f;
            for (int cc = 0; cc < 8; cc++) s += U1[a * 8 + cc] * Wc_s[cc * 64 + o];
            U2[a * 64 + o] = s;
        }
        float s = bci[o];
        for (int j = 0; j < 8; j++) s += Wci_s[o * 8 + j] * bc[j];
        c1[o] = s;
    }
    __syncthreads();  // (3)
    // M = Wmi·U2
    #pragma unroll
    for (int ii = 0; ii < 16; ii++) {
        float s = 0.f;
        for (int a = 0; a < 4; a++) s += Wmi_s[o * 4 + a] * U2[a * 64 + i0 + ii];
        M_s[o * 68 + i0 + ii] = s;
    }
    if (tid < 4) {
        float s = bm[tid];
        for (int i = 0; i < 64; i++) s += Wm_s[tid * 64 + i] * c1[i];
        c2[tid] = s;
    }
    __syncthreads();  // (4)
    // Av = M·Wvi ; ecv = (Wmi·c2 + bmi) + M·bvi
    mm16L(M_s + o * 68, Wvi_s, i0, acc);
    #pragma unroll
    for (int ii = 0; ii < 16; ii++) wsu[8192 + o * 64 + i0 + ii] = f2bf(acc[ii]);
    if (lead) {
        float bvv = 0.f;
        for (int t = 0; t < 64; t++) bvv += M_s[o * 68 + t] * bvi_s[t];
        float cvv = bmi[o];
        for (int a = 0; a < 4; a++) cvv += Wmi_s[o * 4 + a] * c2[a];
        ws[64 + o] = cvv + bvv;
    }
}

// ---------------- KV prepass: grid (8, 64), 4 ktiles/block ----------------
__global__ __launch_bounds__(256)
void qmt_kv(const float* __restrict__ x, float* __restrict__ ws) {
    const int tid = threadIdx.x;
    const int w = tid >> 6;
    const int lane = tid & 63;
    const int ln = lane & 31;
    const int h = lane >> 5;
    const int b = blockIdx.y >> 4;
    const int hh = blockIdx.y & 15;

    const unsigned short* wsu = (const unsigned short*)(ws + 128);
    unsigned short* Kg = (unsigned short*)(ws + 128) + KG_OFF + (size_t)blockIdx.y * (2048 * 64);
    unsigned short* Vg = (unsigned short*)(ws + 128) + VG_OFF + (size_t)blockIdx.y * (64 * 2048);

    const int krl = (w >> 1) * 32 + ln;
    const int dt32 = (w & 1) * 32;

    bf16x8 akf[4], avf[4];
    #pragma unroll
    for (int c = 0; c < 4; c++) {
        int row = dt32 + ln;
        int col = c * 16 + h * 8;
        akf[c] = *(const bf16x8*)(wsu + 4096 + row * 64 + col);
        avf[c] = *(const bf16x8*)(wsu + 8192 + row * 64 + col);
    }
    for (int t = 0; t < 4; t++) {
        const int kt = blockIdx.x * 4 + t;
        bf16x8 xf[4];
        const float* xr = x + ((size_t)(b * SEQ + kt * 64 + krl) * DM + hh * HD);
        #pragma unroll
        for (int c = 0; c < 4; c++) {
            const float* p = xr + c * 16 + h * 8;
            float4 f0 = *(const float4*)p;
            float4 f1 = *(const float4*)(p + 4);
            union { bf16x8 v; unsigned int u[4]; } tt;
            tt.u[0] = pk2t(f0.x, f0.y); tt.u[1] = pk2t(f0.z, f0.w);
            tt.u[2] = pk2t(f1.x, f1.y); tt.u[3] = pk2t(f1.z, f1.w);
            xf[c] = tt.v;
        }
        f32x16 kacc = z16(), vacc = z16();
        #pragma unroll
        for (int c = 0; c < 4; c++) kacc = MFMA32(akf[c], xf[c], kacc, 0, 0, 0);
        #pragma unroll
        for (int c = 0; c < 4; c++) vacc = MFMA32(xf[c], avf[c], vacc, 0, 0, 0);
        #pragma unroll
        for (int g = 0; g < 4; g++) {
            uint2 pk_, pv_;
            pk_.x = pk2r(kacc[4 * g + 0], kacc[4 * g + 1]);
            pk_.y = pk2r(kacc[4 * g + 2], kacc[4 * g + 3]);
            *(uint2*)&Kg[(size_t)(kt * 64 + krl) * 64 + dt32 + 8 * g + 4 * h] = pk_;
            pv_.x = pk2r(vacc[4 * g + 0], vacc[4 * g + 1]);
            pv_.y = pk2r(vacc[4 * g + 2], vacc[4 * g + 3]);
            *(uint2*)&Vg[(size_t)(dt32 + ln) * 2048 + kt * 64 + (w >> 1) * 32 + 8 * g + 4 * h] = pv_;
        }
    }
}

// ---------------- MFMA flash attention ----------------
// grid (16 q-tiles, 64 bh), 256 thr = 4 waves. QT=128, KT=64.
// Single-buffered ks/vt + register-held prefetch; 2 barriers/iter; 4 blocks/CU.
__global__ __launch_bounds__(256, 4)
void qmt_attn2(const float* __restrict__ x, const float* __restrict__ wsf,
               float* __restrict__ out) {
    __shared__ __align__(16) unsigned short ps_s[128 * 72];  // Q pack (prologue) then P; wave-local rows
    __shared__ __align__(16) unsigned short ks_s[64 * 72];   // K [key][dout]
    __shared__ __align__(16) unsigned short vt_s[64 * 72];   // V^T [dout][key]
    __shared__ float als_l[128];
    __shared__ float ls_l[128];

    const int tid = threadIdx.x;
    const int w = tid >> 6;
    const int lane = tid & 63;
    const int ln = lane & 31;
    const int h = lane >> 5;
    const int b = blockIdx.y >> 4;
    const int hh = blockIdx.y & 15;
    const int qbase = blockIdx.x * 128;

    const unsigned short* wsu = (const unsigned short*)(wsf + 128);
    const unsigned short* Kg = wsu + KG_OFF + (size_t)blockIdx.y * (2048 * 64);
    const unsigned short* Vg = wsu + VG_OFF + (size_t)blockIdx.y * (64 * 2048);

    const float ec0 = wsf[64 + ln];
    const float ec1 = wsf[96 + ln];

    // ---- Q projection: Q^T = Aq·x^T (log2-domain scale folded in) ----
    bf16x8 qf[4];
    {
        bf16x8 xq[4];
        const float* xrow = x + ((size_t)(b * SEQ + qbase + w * 32 + ln) * DM + hh * HD);
        #pragma unroll
        for (int c = 0; c < 4; c++) {
            const float* p = xrow + c * 16 + h * 8;
            float4 f0 = *(const float4*)p;
            float4 f1 = *(const float4*)(p + 4);
            union { bf16x8 v; unsigned int u[4]; } t;
            t.u[0] = pk2t(f0.x, f0.y); t.u[1] = pk2t(f0.z, f0.w);
            t.u[2] = pk2t(f1.x, f1.y); t.u[3] = pk2t(f1.z, f1.w);
            xq[c] = t.v;
        }
        #pragma unroll
        for (int m = 0; m < 2; m++) {
            f32x16 acc;
            #pragma unroll
            for (int g = 0; g < 4; g++) {
                float4 b4 = *(const float4*)&wsf[m * 32 + 8 * g + 4 * h];
                acc[4 * g + 0] = b4.x; acc[4 * g + 1] = b4.y;
                acc[4 * g + 2] = b4.z; acc[4 * g + 3] = b4.w;
            }
            #pragma unroll
            for (int c = 0; c < 4; c++) {
                bf16x8 aq = *(const bf16x8*)(wsu + (m * 32 + ln) * 64 + c * 16 + h * 8);
                acc = MFMA32(aq, xq[c], acc, 0, 0, 0);
            }
            #pragma unroll
            for (int g = 0; g < 4; g++) {
                uint2 pw;
                pw.x = pk2r(acc[4 * g + 0], acc[4 * g + 1]);
                pw.y = pk2r(acc[4 * g + 2], acc[4 * g + 3]);
                *(uint2*)&ps_s[(w * 32 + ln) * 72 + m * 32 + 8 * g + 4 * h] = pw;
            }
        }
        #pragma unroll
        for (int c = 0; c < 4; c++)
            qf[c] = *(const bf16x8*)&ps_s[(w * 32 + ln) * 72 + c * 16 + h * 8];
    }

    f32x16 o0 = z16(), o1 = z16();
    float m_i = -1e30f, l_i = 0.f;

    // staging: thread handles rows (srow, srow+32), 16B column chunk scol
    const int srow = tid >> 3;
    const int scol = (tid & 7) * 8;

    u16x8 ka, kb, va, vb;
    ka = *(const u16x8*)(Kg + (size_t)srow * 64 + scol);
    kb = *(const u16x8*)(Kg + (size_t)(srow + 32) * 64 + scol);
    va = *(const u16x8*)(Vg + (size_t)srow * 2048 + scol);
    vb = *(const u16x8*)(Vg + (size_t)(srow + 32) * 2048 + scol);
    *(u16x8*)&ks_s[srow * 72 + scol] = ka;
    *(u16x8*)&ks_s[(srow + 32) * 72 + scol] = kb;
    *(u16x8*)&vt_s[srow * 72 + scol] = va;
    *(u16x8*)&vt_s[(srow + 32) * 72 + scol] = vb;
    __syncthreads();

    for (int kt = 0; kt < SEQ / 64; kt++) {
        const bool more = (kt < SEQ / 64 - 1);
        if (more) {  // prefetch next tile into registers
            const int kn = (kt + 1) * 64;
            ka = *(const u16x8*)(Kg + (size_t)(kn + srow) * 64 + scol);
            kb = *(const u16x8*)(Kg + (size_t)(kn + srow + 32) * 64 + scol);
            va = *(const u16x8*)(Vg + (size_t)srow * 2048 + kn + scol);
            vb = *(const u16x8*)(Vg + (size_t)(srow + 32) * 2048 + kn + scol);
        }

        // ---- S^T = K·Q^T (log2 domain) + online softmax via exp2 ----
        f32x16 st0 = z16(), st1 = z16();
        #pragma unroll
        for (int c = 0; c < 4; c++) {
            bf16x8 k0 = *(const bf16x8*)&ks_s[ln * 72 + c * 16 + h * 8];
            bf16x8 k1 = *(const bf16x8*)&ks_s[(32 + ln) * 72 + c * 16 + h * 8];
            st0 = MFMA32(k0, qf[c], st0, 0, 0, 0);
            st1 = MFMA32(k1, qf[c], st1, 0, 0, 0);
        }
        float mx = st0[0];
        #pragma unroll
        for (int i = 1; i < 16; i++) mx = fmaxf(mx, st0[i]);
        #pragma unroll
        for (int i = 0; i < 16; i++) mx = fmaxf(mx, st1[i]);
        mx = fmaxf(mx, __shfl_xor(mx, 32));
        const float mn = fmaxf(m_i, mx);
        const float al = EXP2(m_i - mn);
        float ss = 0.f;
        #pragma unroll
        for (int i = 0; i < 16; i++) { st0[i] = EXP2(st0[i] - mn); ss += st0[i]; }
        #pragma unroll
        for (int i = 0; i < 16; i++) { st1[i] = EXP2(st1[i] - mn); ss += st1[i]; }
        ss += __shfl_xor(ss, 32);
        l_i = l_i * al + ss;
        m_i = mn;
        if (lane < 32) als_l[w * 32 + lane] = al;
        #pragma unroll
        for (int g = 0; g < 4; g++) {
            uint2 p0, p1;
            p0.x = pk2r(st0[4 * g + 0], st0[4 * g + 1]);
            p0.y = pk2r(st0[4 * g + 2], st0[4 * g + 3]);
            *(uint2*)&ps_s[(w * 32 + ln) * 72 + 8 * g + 4 * h] = p0;
            p1.x = pk2r(st1[4 * g + 0], st1[4 * g + 1]);
            p1.y = pk2r(st1[4 * g + 2], st1[4 * g + 3]);
            *(uint2*)&ps_s[(w * 32 + ln) * 72 + 32 + 8 * g + 4 * h] = p1;
        }
        #pragma unroll
        for (int g = 0; g < 4; g++) {  // rescale O by alpha[q]
            float4 a4 = *(const float4*)&als_l[w * 32 + 8 * g + 4 * h];
            o0[4 * g + 0] *= a4.x; o0[4 * g + 1] *= a4.y;
            o0[4 * g + 2] *= a4.z; o0[4 * g + 3] *= a4.w;
            o1[4 * g + 0] *= a4.x; o1[4 * g + 1] *= a4.y;
            o1[4 * g + 2] *= a4.z; o1[4 * g + 3] *= a4.w;
        }
        // ---- O += P·V ----
        #pragma unroll
        for (int c = 0; c < 4; c++) {
            bf16x8 pf = *(const bf16x8*)&ps_s[(w * 32 + ln) * 72 + c * 16 + h * 8];
            bf16x8 v0 = *(const bf16x8*)&vt_s[ln * 72 + c * 16 + h * 8];
            bf16x8 v1 = *(const bf16x8*)&vt_s[(32 + ln) * 72 + c * 16 + h * 8];
            o0 = MFMA32(pf, v0, o0, 0, 0, 0);
            o1 = MFMA32(pf, v1, o1, 0, 0, 0);
        }
        __syncthreads();  // (i) all reads of ks/vt done
        if (more) {
            *(u16x8*)&ks_s[srow * 72 + scol] = ka;
            *(u16x8*)&ks_s[(srow + 32) * 72 + scol] = kb;
            *(u16x8*)&vt_s[srow * 72 + scol] = va;
            *(u16x8*)&vt_s[(srow + 32) * 72 + scol] = vb;
        }
        __syncthreads();  // (ii) next tile visible
    }

    // ---- epilogue ----
    if (lane < 32) ls_l[w * 32 + lane] = l_i;
    #pragma unroll
    for (int g = 0; g < 4; g++) {
        float4 l4 = *(const float4*)&ls_l[w * 32 + 8 * g + 4 * h];
        float4 iv = make_float4(1.f / l4.x, 1.f / l4.y, 1.f / l4.z, 1.f / l4.w);
        #pragma unroll
        for (int i = 0; i < 4; i++) {
            float ivv = (i == 0) ? iv.x : (i == 1) ? iv.y : (i == 2) ? iv.z : iv.w;
            int q = qbase + w * 32 + 8 * g + 4 * h + i;
            float* orow = out + ((size_t)(b * SEQ + q) * DM + hh * HD);
            orow[ln] = o0[4 * g + i] * ivv + ec0;
            orow[32 + ln] = o1[4 * g + i] * ivv + ec1;
        }
    }
}

// ---------------- fallback attention (in-loop KV projection) ----------------
__global__ __launch_bounds__(256, 3)
void qmt_attn_fb(const float* __restrict__ x, const float* __restrict__ wsf,
                 float* __restrict__ out) {
    __shared__ __align__(16) unsigned short ps_s[128 * 72];
    __shared__ __align__(16) unsigned short ks_s[64 * 72];
    __shared__ __align__(16) unsigned short vt_s[64 * 72];
    __shared__ float als_l[128];
    __shared__ float ls_l[128];

    const int tid = threadIdx.x;
    const int w = tid >> 6;
    const int lane = tid & 63;
    const int ln = lane & 31;
    const int h = lane >> 5;
    const int b = blockIdx.y >> 4;
    const int hh = blockIdx.y & 15;
    const int qbase = blockIdx.x * 128;

    const unsigned short* wsu = (const unsigned short*)(wsf + 128);

    bf16x8 akf[4], avf[4];
    #pragma unroll
    for (int c = 0; c < 4; c++) {
        int row = (w & 1) * 32 + ln;
        int col = c * 16 + h * 8;
        akf[c] = *(const bf16x8*)(wsu + 4096 + row * 64 + col);
        avf[c] = *(const bf16x8*)(wsu + 8192 + row * 64 + col);
    }
    const float ec0 = wsf[64 + ln];
    const float ec1 = wsf[96 + ln];

    bf16x8 qf[4];
    {
        bf16x8 xq[4];
        const float* xrow = x + ((size_t)(b * SEQ + qbase + w * 32 + ln) * DM + hh * HD);
        #pragma unroll
        for (int c = 0; c < 4; c++) {
            const float* p = xrow + c * 16 + h * 8;
            float4 f0 = *(const float4*)p;
            float4 f1 = *(const float4*)(p + 4);
            union { bf16x8 v; unsigned int u[4]; } t;
            t.u[0] = pk2t(f0.x, f0.y); t.u[1] = pk2t(f0.z, f0.w);
            t.u[2] = pk2t(f1.x, f1.y); t.u[3] = pk2t(f1.z, f1.w);
            xq[c] = t.v;
        }
        #pragma unroll
        for (int m = 0; m < 2; m++) {
            f32x16 acc;
            #pragma unroll
            for (int g = 0; g < 4; g++) {
                float4 b4 = *(const float4*)&wsf[m * 32 + 8 * g + 4 * h];
                acc[4 * g + 0] = b4.x; acc[4 * g + 1] = b4.y;
                acc[4 * g + 2] = b4.z; acc[4 * g + 3] = b4.w;
            }
            #pragma unroll
            for (int c = 0; c < 4; c++) {
                bf16x8 aq = *(const bf16x8*)(wsu + (m * 32 + ln) * 64 + c * 16 + h * 8);
                acc = MFMA32(aq, xq[c], acc, 0, 0, 0);
            }
            #pragma unroll
            for (int g = 0; g < 4; g++) {
                uint2 pw;
                pw.x = pk2r(acc[4 * g + 0], acc[4 * g + 1]);
                pw.y = pk2r(acc[4 * g + 2], acc[4 * g + 3]);
                *(uint2*)&ps_s[(w * 32 + ln) * 72 + m * 32 + 8 * g + 4 * h] = pw;
            }
        }
        #pragma unroll
        for (int c = 0; c < 4; c++)
            qf[c] = *(const bf16x8*)&ps_s[(w * 32 + ln) * 72 + c * 16 + h * 8];
    }

    f32x16 o0 = z16(), o1 = z16();
    float m_i = -1e30f, l_i = 0.f;

    const int krl = (w >> 1) * 32 + ln;
    const int dt32 = (w & 1) * 32;

    for (int kt = 0; kt < SEQ / 64; kt++) {
        bf16x8 xf[4];
        const float* xr = x + ((size_t)(b * SEQ + kt * 64 + krl) * DM + hh * HD);
        #pragma unroll
        for (int c = 0; c < 4; c++) {
            const float* p = xr + c * 16 + h * 8;
            float4 f0 = *(const float4*)p;
            float4 f1 = *(const float4*)(p + 4);
            union { bf16x8 v; unsigned int u[4]; } t;
            t.u[0] = pk2t(f0.x, f0.y); t.u[1] = pk2t(f0.z, f0.w);
            t.u[2] = pk2t(f1.x, f1.y); t.u[3] = pk2t(f1.z, f1.w);
            xf[c] = t.v;
        }
        f32x16 kacc = z16(), vacc = z16();
        #pragma unroll
        for (int c = 0; c < 4; c++) kacc = MFMA32(akf[c], xf[c], kacc, 0, 0, 0);
        #pragma unroll
        for (int c = 0; c < 4; c++) vacc = MFMA32(xf[c], avf[c], vacc, 0, 0, 0);
        #pragma unroll
        for (int g = 0; g < 4; g++) {
            uint2 pk_, pv_;
            pk_.x = pk2r(kacc[4 * g + 0], kacc[4 * g + 1]);
            pk_.y = pk2r(kacc[4 * g + 2], kacc[4 * g + 3]);
            *(uint2*)&ks_s[krl * 72 + dt32 + 8 * g + 4 * h] = pk_;
            pv_.x = pk2r(vacc[4 * g + 0], vacc[4 * g + 1]);
            pv_.y = pk2r(vacc[4 * g + 2], vacc[4 * g + 3]);
            *(uint2*)&vt_s[(dt32 + ln) * 72 + (w >> 1) * 32 + 8 * g + 4 * h] = pv_;
        }
        __syncthreads();

        f32x16 st0 = z16(), st1 = z16();
        #pragma unroll
        for (int c = 0; c < 4; c++) {
            bf16x8 k0 = *(const bf16x8*)&ks_s[ln * 72 + c * 16 + h * 8];
            bf16x8 k1 = *(const bf16x8*)&ks_s[(32 + ln) * 72 + c * 16 + h * 8];
            st0 = MFMA32(k0, qf[c], st0, 0, 0, 0);
            st1 = MFMA32(k1, qf[c], st1, 0, 0, 0);
        }
        float mx = st0[0];
        #pragma unroll
        for (int i = 1; i < 16; i++) mx = fmaxf(mx, st0[i]);
        #pragma unroll
        for (int i = 0; i < 16; i++) mx = fmaxf(mx, st1[i]);
        mx = fmaxf(mx, __shfl_xor(mx, 32));
        const float mn = fmaxf(m_i, mx);
        const float al = EXP2(m_i - mn);
        float ss = 0.f;
        #pragma unroll
        for (int i = 0; i < 16; i++) { st0[i] = EXP2(st0[i] - mn); ss += st0[i]; }
        #pragma unroll
        for (int i = 0; i < 16; i++) { st1[i] = EXP2(st1[i] - mn); ss += st1[i]; }
        ss += __shfl_xor(ss, 32);
        l_i = l_i * al + ss;
        m_i = mn;
        if (lane < 32) als_l[w * 32 + lane] = al;
        #pragma unroll
        for (int g = 0; g < 4; g++) {
            uint2 p0, p1;
            p0.x = pk2r(st0[4 * g + 0], st0[4 * g + 1]);
            p0.y = pk2r(st0[4 * g + 2], st0[4 * g + 3]);
            *(uint2*)&ps_s[(w * 32 + ln) * 72 + 8 * g + 4 * h] = p0;
            p1.x = pk2r(st1[4 * g + 0], st1[4 * g + 1]);
            p1.y = pk2r(st1[4 * g + 2], st1[4 * g + 3]);
            *(uint2*)&ps_s[(w * 32 + ln) * 72 + 32 + 8 * g + 4 * h] = p1;
        }
        #pragma unroll
        for (int g = 0; g < 4; g++) {
            float4 a4 = *(const float4*)&als_l[w * 32 + 8 * g + 4 * h];
            o0[4 * g + 0] *= a4.x; o0[4 * g + 1] *= a4.y;
            o0[4 * g + 2] *= a4.z; o0[4 * g + 3] *= a4.w;
            o1[4 * g + 0] *= a4.x; o1[4 * g + 1] *= a4.y;
            o1[4 * g + 2] *= a4.z; o1[4 * g + 3] *= a4.w;
        }
        #pragma unroll
        for (int c = 0; c < 4; c++) {
            bf16x8 pf = *(const bf16x8*)&ps_s[(w * 32 + ln) * 72 + c * 16 + h * 8];
            bf16x8 v0 = *(const bf16x8*)&vt_s[ln * 72 + c * 16 + h * 8];
            bf16x8 v1 = *(const bf16x8*)&vt_s[(32 + ln) * 72 + c * 16 + h * 8];
            o0 = MFMA32(pf, v0, o0, 0, 0, 0);
            o1 = MFMA32(pf, v1, o1, 0, 0, 0);
        }
        __syncthreads();
    }

    if (lane < 32) ls_l[w * 32 + lane] = l_i;
    #pragma unroll
    for (int g = 0; g < 4; g++) {
        float4 l4 = *(const float4*)&ls_l[w * 32 + 8 * g + 4 * h];
        float4 iv = make_float4(1.f / l4.x, 1.f / l4.y, 1.f / l4.z, 1.f / l4.w);
        #pragma unroll
        for (int i = 0; i < 4; i++) {
            float ivv = (i == 0) ? iv.x : (i == 1) ? iv.y : (i == 2) ? iv.z : iv.w;
            int q = qbase + w * 32 + 8 * g + 4 * h + i;
            float* orow = out + ((size_t)(b * SEQ + q) * DM + hh * HD);
            orow[ln] = o0[4 * g + i] * ivv + ec0;
            orow[32 + ln] = o1[4 * g + i] * ivv + ec1;
        }
    }
}

extern "C" void kernel_launch(void* const* d_in, const int* in_sizes, int n_in,
                              void* d_out, int out_size, void* d_ws, size_t ws_size,
                              hipStream_t stream) {
    const float* x = (const float*)d_in[0];
    float* wsf = (float*)d_ws;

    qmt_combine<<<1, 256, 0, stream>>>(
        (const float*)d_in[1],  (const float*)d_in[2],
        (const float*)d_in[3],  (const float*)d_in[4],
        (const float*)d_in[5],  (const float*)d_in[6],
        (const float*)d_in[7],  (const float*)d_in[8],
        (const float*)d_in[9],  (const float*)d_in[10],
        (const float*)d_in[11], (const float*)d_in[12],
        (const float*)d_in[13], (const float*)d_in[14],
        (const float*)d_in[15], (const float*)d_in[16],
        wsf);

    if (ws_size >= WS_NEED) {
        dim3 gkv(SEQ / 256, 64);
        qmt_kv<<<gkv, 256, 0, stream>>>(x, wsf);
        dim3 grid(SEQ / 128, 64);
        qmt_attn2<<<grid, 256, 0, stream>>>(x, wsf, (float*)d_out);
    } else {
        dim3 grid(SEQ / 128, 64);
        qmt_attn_fb<<<grid, 256, 0, stream>>>(x, wsf, (float*)d_out);
    }
}